// Round 6
// baseline (4318.774 us; speedup 1.0000x reference)
//
#include <hip/hip_runtime.h>
#include <math.h>

typedef unsigned short u16;
typedef unsigned int u32;
typedef float f32x4 __attribute__((ext_vector_type(4)));
typedef short bfrag __attribute__((ext_vector_type(8)));

#define HS 128

__device__ __forceinline__ float sigf(float x) { return 1.0f / (1.0f + __expf(-x)); }
__device__ __forceinline__ float tanhfast(float x) {
    float e = __expf(2.0f * x);
    return 1.0f - 2.0f / (e + 1.0f);
}
__device__ __forceinline__ u16 f2bf(float f) {
    u32 u = __float_as_uint(f);
    return (u16)((u + 0x7FFFu + ((u >> 16) & 1u)) >> 16);
}
__device__ __forceinline__ float bf2f(u16 h) { return __uint_as_float(((u32)h) << 16); }

// B' value: rows 0-127 emb:[W_iou|W_f|W_f], 128-255 hl:[U_iou|U_f|0], 256-383 hr:[U_iou|0|U_f]
__device__ __forceinline__ float bval_int(int k, int col,
    const float* W_iou, const float* W_f, const float* U_iou, const float* U_f)
{
    if (col < 384) {
        if (k < 128) return W_iou[k * 384 + col];
        if (k < 256) return U_iou[(k - 128) * 384 + col];
        return U_iou[(k - 256) * 384 + col];
    } else if (col < 512) {
        int cc = col - 384;
        if (k < 128) return W_f[k * 128 + cc];
        if (k < 256) return U_f[(k - 128) * 128 + cc];
        return 0.0f;
    } else {
        int cc = col - 512;
        if (k < 128) return W_f[k * 128 + cc];
        if (k < 256) return 0.0f;
        return U_f[(k - 256) * 128 + cc];
    }
}

// ---------------- prep (round-5 verbatim) ----------------
#define TOT_INT (12 * 40 * 2 * 512)        // 491520
#define TOT_LEAF (4 * 24 * 2 * 512)        // 98304
#define ZBF_OFF (TOT_INT + TOT_LEAF)       // 589824
#define EPL_OFF (ZBF_OFF + 128)            // 589952
#define TOT_E 4096000
#define ZBP_OFF (EPL_OFF + TOT_E)          // 4685952
#define PREP_ALL (ZBP_OFF + 128)           // 4686080

__global__ __launch_bounds__(256) void prep_kernel(
    const float* __restrict__ W_iou, const float* __restrict__ W_f,
    const float* __restrict__ U_iou, const float* __restrict__ U_f,
    const float* __restrict__ E,
    u16* __restrict__ Bint, u16* __restrict__ Bleaf,
    u16* __restrict__ EH, u16* __restrict__ EL,
    u16* __restrict__ zbp, float* __restrict__ zbf, int do_planes)
{
    int idx = blockIdx.x * 256 + threadIdx.x;
    if (idx < TOT_INT) {
        int j = idx & 7, l = (idx >> 3) & 63, half = (idx >> 9) & 1;
        int rest = idx >> 10;
        int cfabs = rest % 40, kc = rest / 40;
        int colp = cfabs * 16 + (l & 15);
        int wc = colp / 160, q = colp - wc * 160;
        int g = q >> 5, j0 = 32 * wc + (q & 31);
        int origcol = (g < 3) ? g * 128 + j0 : ((g == 3) ? 384 + j0 : 512 + j0);
        int k = kc * 32 + (l >> 4) * 8 + j;
        float v = bval_int(k, origcol, W_iou, W_f, U_iou, U_f);
        u16 hi = f2bf(v);
        Bint[idx] = half ? f2bf(v - bf2f(hi)) : hi;
    } else if (idx < TOT_INT + TOT_LEAF) {
        int i2 = idx - TOT_INT;
        int j = i2 & 7, l = (i2 >> 3) & 63, half = (i2 >> 9) & 1;
        int rest = i2 >> 10;
        int cfabs = rest % 24, kc = rest / 24;
        int colp = cfabs * 16 + (l & 15);
        int wc = colp / 96, q = colp - wc * 96;
        int g = q >> 5, j0 = 32 * wc + (q & 31);
        int origcol = g * 128 + j0;
        int k = kc * 32 + (l >> 4) * 8 + j;
        float v = W_iou[k * 384 + origcol];
        u16 hi = f2bf(v);
        Bleaf[i2] = half ? f2bf(v - bf2f(hi)) : hi;
    } else if (idx < EPL_OFF) {
        zbf[idx - ZBF_OFF] = 0.0f;
    } else if (do_planes) {
        if (idx < ZBP_OFF) {
            int i3 = idx - EPL_OFF;
            float v = E[i3];
            u16 hi = f2bf(v);
            EH[i3] = hi;
            EL[i3] = f2bf(v - bf2f(hi));
        } else if (idx < PREP_ALL) {
            zbp[idx - ZBP_OFF] = 0;
        }
    }
}

// ---------------- fused level GEMM + LSTM cell ----------------
// 1024 thr = 16 waves (4 row x 4 col). BM=128, BK=32. Wave tile 32 x (NCF*16).
// A: bf16 hi/lo planes via global_load_lds, quad-buffered 3-ahead.
// B: direct global->reg, pre-layouted per-(kc,wc,cf) 1KB lines (L1 dedups the 4 wr-waves).
template<int NKC, int NCFA, int NG, bool INTERNAL, bool PLANES>
__global__ __launch_bounds__(1024, 4) void gemm_lvl(
    const int* __restrict__ x, const int* __restrict__ mask,
    const float* __restrict__ E,
    const u16* __restrict__ EH, const u16* __restrict__ EL,
    const u16* __restrict__ zbp, const float* __restrict__ zbf,
    const u16* __restrict__ Bg,
    const float* __restrict__ b_iou_x, const float* __restrict__ b_f_x,
    const float* __restrict__ b_iou_h, const float* __restrict__ b_f_h,
    float* __restrict__ h, float* __restrict__ c,
    u16* __restrict__ hbH, u16* __restrict__ hbL, int s0, int M)
{
    constexpr int NCF = 2 * NG;
    constexpr int NB = 2 * NCF;   // B vmem loads per iter
    __shared__ __align__(16) u16 ldsRaw[4 * 8192];   // 64 KB: 4 bufs x (128 rows x 32 k x hi/lo)
    u16* ldsAp = ldsRaw;
    float* ldsAf = (float*)ldsRaw;
    const int t = threadIdx.x;
    const int n0 = s0 + blockIdx.x * 128;
    const int lastn = s0 + M;
    const int l = t & 63, wid = t >> 6;
    const int wr = wid >> 2, wc = wid & 3;
    const int lr = l & 15, lg = l >> 4;

    // ---- staging source precompute (no loads inside K-loop) ----
    const u16 *ebp = nullptr, *hb1p = nullptr, *hb2p = nullptr;
    const float *Ebf = nullptr, *h1f = nullptr, *h2f = nullptr;
    int fkof = 0;
    if constexpr (PLANES) {
        const int prow = t & 127;                 // node row 0..127
        const int plgs8 = ((t >> 7) & 3) * 8;     // k-slot offset within 32-chunk
        const int pp = t >> 9;                    // plane: 0=hi, 1=lo
        int ns = n0 + prow; if (ns >= lastn) ns = s0;
        const u16* Ep = pp ? EL : EH;
        ebp = (mask[ns] ? (Ep + (size_t)x[ns] * HS) : zbp) + plgs8;
        if constexpr (INTERNAL) {
            const u16* hbp = pp ? hbL : hbH;
            hb1p = hbp + (size_t)(2 * ns + 1) * HS + plgs8;
            hb2p = hbp + (size_t)(2 * ns + 2) * HS + plgs8;
        }
    } else {
        const int frow = t >> 3;                  // 0..127
        fkof = ((t & 7) ^ (frow & 7)) * 4;
        int ns = n0 + frow; if (ns >= lastn) ns = s0;
        Ebf = mask[ns] ? (E + (size_t)x[ns] * HS) : zbf;
        if constexpr (INTERNAL) {
            h1f = h + (size_t)(2 * ns + 1) * HS - 128;
            h2f = h + (size_t)(2 * ns + 2) * HS - 256;
        }
    }

    auto stageA = [&](int kc, int buf) {
        if constexpr (PLANES) {
            const u16* src;
            if constexpr (INTERNAL) {
                int seg = kc >> 2, ks = kc & 3;
                src = (seg == 0 ? ebp : (seg == 1 ? hb1p : hb2p)) + ks * 32;
            } else {
                src = ebp + kc * 32;
            }
            __builtin_amdgcn_global_load_lds(
                (const __attribute__((address_space(1))) void*)src,
                (__attribute__((address_space(3))) void*)(ldsAp + buf * 8192 + t * 8), 16, 0, 0);
        } else {
            int k = kc * 32 + fkof;
            const float* src = Ebf + k;
            if constexpr (INTERNAL) {
                if (k >= 128) src = h1f + k;
                if (k >= 256) src = h2f + k;
            }
            __builtin_amdgcn_global_load_lds(
                (const __attribute__((address_space(1))) void*)src,
                (__attribute__((address_space(3))) void*)(ldsAf + buf * 4096 + t * 4), 16, 0, 0);
        }
    };

    f32x4 acc[2][NCF];
    const f32x4 zzz = {0.0f, 0.0f, 0.0f, 0.0f};
#pragma unroll
    for (int rf = 0; rf < 2; ++rf)
#pragma unroll
        for (int cf = 0; cf < NCF; ++cf) acc[rf][cf] = zzz;

    stageA(0, 0);
    stageA(1, 1);
    stageA(2, 2);

#pragma unroll 1
    for (int kc = 0; kc < NKC; ++kc) {
        bfrag bh[NCF], bl[NCF];
        const u16* bp = Bg + ((size_t)(kc * NCFA + wc * NCF) * 2) * 512 + l * 8;
#pragma unroll
        for (int cf = 0; cf < NCF; ++cf) {
            bh[cf] = *(const bfrag*)(bp + (size_t)cf * 1024);
            bl[cf] = *(const bfrag*)(bp + (size_t)cf * 1024 + 512);
        }
        // retire A(kc): outstanding after wait = 2 newer DMAs + NB B-loads
        asm volatile("s_waitcnt vmcnt(%0)" :: "i"(NB + 2) : "memory");
        __builtin_amdgcn_s_barrier();
        asm volatile("" ::: "memory");
        { int kn = kc + 3; if (kn > NKC - 1) kn = NKC - 1; stageA(kn, (kc + 3) & 3); }

        bfrag ah[2], al[2];
        if constexpr (PLANES) {
            const u16* ab = ldsAp + (kc & 3) * 8192;
#pragma unroll
            for (int rf = 0; rf < 2; ++rf) {
                int arow = 32 * wr + 16 * rf + lr;
                ah[rf] = *(const bfrag*)(ab + lg * 1024 + arow * 8);
                al[rf] = *(const bfrag*)(ab + 4096 + lg * 1024 + arow * 8);
            }
        } else {
            const float* abase = ldsAf + (kc & 3) * 4096;
#pragma unroll
            for (int rf = 0; rf < 2; ++rf) {
                int arow = 32 * wr + 16 * rf + lr;
                int rs = lr & 7;
                const float* rbase = abase + arow * 32;
                f32x4 v0 = *(const f32x4*)(rbase + (((2 * lg) ^ rs) << 2));
                f32x4 v1 = *(const f32x4*)(rbase + (((2 * lg + 1) ^ rs) << 2));
                bfrag H, L;
#pragma unroll
                for (int j = 0; j < 4; ++j) {
                    u32 u = __float_as_uint(v0[j]);
                    u32 hu = u & 0xFFFF0000u;
                    H[j] = (short)(hu >> 16);
                    L[j] = (short)f2bf(v0[j] - __uint_as_float(hu));
                }
#pragma unroll
                for (int j = 0; j < 4; ++j) {
                    u32 u = __float_as_uint(v1[j]);
                    u32 hu = u & 0xFFFF0000u;
                    H[4 + j] = (short)(hu >> 16);
                    L[4 + j] = (short)f2bf(v1[j] - __uint_as_float(hu));
                }
                ah[rf] = H; al[rf] = L;
            }
        }

#pragma unroll
        for (int cf = 0; cf < NCF; ++cf) {
            acc[0][cf] = __builtin_amdgcn_mfma_f32_16x16x32_bf16(ah[0], bh[cf], acc[0][cf], 0, 0, 0);
            acc[1][cf] = __builtin_amdgcn_mfma_f32_16x16x32_bf16(ah[1], bh[cf], acc[1][cf], 0, 0, 0);
            acc[0][cf] = __builtin_amdgcn_mfma_f32_16x16x32_bf16(al[0], bh[cf], acc[0][cf], 0, 0, 0);
            acc[1][cf] = __builtin_amdgcn_mfma_f32_16x16x32_bf16(al[1], bh[cf], acc[1][cf], 0, 0, 0);
            acc[0][cf] = __builtin_amdgcn_mfma_f32_16x16x32_bf16(ah[0], bl[cf], acc[0][cf], 0, 0, 0);
            acc[1][cf] = __builtin_amdgcn_mfma_f32_16x16x32_bf16(ah[1], bl[cf], acc[1][cf], 0, 0, 0);
        }
    }

    // ---- register-local epilogue (round-5 verbatim, wr now 0..3) ----
#pragma unroll
    for (int hi = 0; hi < 2; ++hi) {
        int j = 32 * wc + 16 * hi + lr;
        float bix = b_iou_x[j], box = b_iou_x[HS + j], bux = b_iou_x[2 * HS + j];
        float bih = b_iou_h[j], boh = b_iou_h[HS + j], buh = b_iou_h[2 * HS + j];
        float bfx = 0.0f, bfh = 0.0f;
        if constexpr (INTERNAL) { bfx = b_f_x[j]; bfh = b_f_h[j]; }
#pragma unroll
        for (int rf = 0; rf < 2; ++rf) {
#pragma unroll
            for (int r = 0; r < 4; ++r) {
                int n = n0 + 32 * wr + 16 * rf + 4 * lg + r;
                if (n >= lastn) continue;
                float m = (float)mask[n];
                float iv = acc[rf][0 + hi][r] + m * bix + bih;
                float ov = acc[rf][2 + hi][r] + m * box + boh;
                float uv = acc[rf][4 + hi][r] + m * bux + buh;
                float cn;
                if constexpr (INTERNAL) {
                    float fl = acc[rf][6 + hi][r] + m * bfx + bfh;
                    float fr = acc[rf][8 + hi][r] + m * bfx + bfh;
                    float cl = c[(size_t)(2 * n + 1) * HS + j];
                    float cr = c[(size_t)(2 * n + 2) * HS + j];
                    cn = sigf(iv) * tanhfast(uv) + sigf(fl) * cl + sigf(fr) * cr;
                } else {
                    cn = sigf(iv) * tanhfast(uv);
                }
                float hn = sigf(ov) * tanhfast(cn);
                c[(size_t)n * HS + j] = cn;
                h[(size_t)n * HS + j] = hn;
                if constexpr (PLANES) {
                    u16 hh = f2bf(hn);
                    hbH[(size_t)n * HS + j] = hh;
                    hbL[(size_t)n * HS + j] = f2bf(hn - bf2f(hh));
                }
            }
        }
    }
}

extern "C" void kernel_launch(void* const* d_in, const int* in_sizes, int n_in,
                              void* d_out, int out_size, void* d_ws, size_t ws_size,
                              hipStream_t stream)
{
    const int*   x       = (const int*)d_in[0];
    const int*   mask    = (const int*)d_in[1];
    const float* E       = (const float*)d_in[2];
    const float* W_iou   = (const float*)d_in[3];
    const float* b_iou_x = (const float*)d_in[4];
    const float* W_f     = (const float*)d_in[5];
    const float* b_f_x   = (const float*)d_in[6];
    const float* U_iou   = (const float*)d_in[7];
    const float* b_iou_h = (const float*)d_in[8];
    const float* U_f     = (const float*)d_in[9];
    const float* b_f_h   = (const float*)d_in[10];

    float* h = (float*)d_out;
    char* ws = (char*)d_ws;

    u16*   Bint  = (u16*)(ws);                      // 983,040
    u16*   Bleaf = (u16*)(ws + 983040);             // 196,608 -> 1,179,648
    float* zbf   = (float*)(ws + 1179648);          // 512     -> 1,180,160

    const size_t NEED = 285998848ull;
    bool planes = ws_size >= NEED;

    if (planes) {
        u16*   EH  = (u16*)(ws + 1180160);           // 8,192,000  -> 9,372,160
        u16*   EL  = (u16*)(ws + 9372160);           // 8,192,000  -> 17,564,160
        u16*   zbp = (u16*)(ws + 17564160);          // 256        -> 17,564,416
        float* c   = (float*)(ws + 17564416);        // 134,217,216 -> 151,781,632
        u16*   hbH = (u16*)(ws + 151781632);         // 67,108,608  -> 218,890,240
        u16*   hbL = (u16*)(ws + 218890240);         // 67,108,608  -> 285,998,848

        prep_kernel<<<PREP_ALL / 256, 256, 0, stream>>>(
            W_iou, W_f, U_iou, U_f, E, Bint, Bleaf, EH, EL, zbp, zbf, 1);

        {   // leaves, lvl = 17: K=128 (4 kc), 384 cols
            int s0 = (1 << 17) - 1, M = 1 << 17;
            gemm_lvl<4, 24, 3, false, true><<<M / 128, 1024, 0, stream>>>(
                x, mask, E, EH, EL, zbp, zbf, Bleaf,
                b_iou_x, b_f_x, b_iou_h, b_f_h, h, c, hbH, hbL, s0, M);
        }
        for (int lvl = 16; lvl >= 0; --lvl) {
            int s0 = (1 << lvl) - 1, M = 1 << lvl;
            int blocks = (M + 127) / 128;
            gemm_lvl<12, 40, 5, true, true><<<blocks, 1024, 0, stream>>>(
                x, mask, E, EH, EL, zbp, zbf, Bint,
                b_iou_x, b_f_x, b_iou_h, b_f_h, h, c, hbH, hbL, s0, M);
        }
    } else {
        float* c = (float*)(ws + 1180160);
        prep_kernel<<<(EPL_OFF + 255) / 256, 256, 0, stream>>>(
            W_iou, W_f, U_iou, U_f, E, Bint, Bleaf, nullptr, nullptr, nullptr, zbf, 0);

        {   // leaves
            int s0 = (1 << 17) - 1, M = 1 << 17;
            gemm_lvl<4, 24, 3, false, false><<<M / 128, 1024, 0, stream>>>(
                x, mask, E, nullptr, nullptr, nullptr, zbf, Bleaf,
                b_iou_x, b_f_x, b_iou_h, b_f_h, h, c, nullptr, nullptr, s0, M);
        }
        for (int lvl = 16; lvl >= 0; --lvl) {
            int s0 = (1 << lvl) - 1, M = 1 << lvl;
            int blocks = (M + 127) / 128;
            gemm_lvl<12, 40, 5, true, false><<<blocks, 1024, 0, stream>>>(
                x, mask, E, nullptr, nullptr, nullptr, zbf, Bint,
                b_iou_x, b_f_x, b_iou_h, b_f_h, h, c, nullptr, nullptr, s0, M);
        }
    }
}

// Round 7
// 994.017 us; speedup vs baseline: 4.3448x; 4.3448x over previous
//
#include <hip/hip_runtime.h>
#include <math.h>

typedef unsigned short u16;
typedef unsigned int u32;
typedef float f32x4 __attribute__((ext_vector_type(4)));
typedef short bfrag __attribute__((ext_vector_type(8)));

#define HS 128
#define DPLANE 4096000      // EL - EH, in u16 elements
#define DHB    33554304     // hbL - hbH, in u16 elements

__device__ __forceinline__ float sigf(float x) { return 1.0f / (1.0f + __expf(-x)); }
__device__ __forceinline__ float tanhfast(float x) {
    float e = __expf(2.0f * x);
    return 1.0f - 2.0f / (e + 1.0f);
}
__device__ __forceinline__ u16 f2bf(float f) {
    u32 u = __float_as_uint(f);
    return (u16)((u + 0x7FFFu + ((u >> 16) & 1u)) >> 16);
}
__device__ __forceinline__ float bf2f(u16 h) { return __uint_as_float(((u32)h) << 16); }

// B' value: rows 0-127 emb:[W_iou|W_f|W_f], 128-255 hl:[U_iou|U_f|0], 256-383 hr:[U_iou|0|U_f]
__device__ __forceinline__ float bval_int(int k, int col,
    const float* W_iou, const float* W_f, const float* U_iou, const float* U_f)
{
    if (col < 384) {
        if (k < 128) return W_iou[k * 384 + col];
        if (k < 256) return U_iou[(k - 128) * 384 + col];
        return U_iou[(k - 256) * 384 + col];
    } else if (col < 512) {
        int cc = col - 384;
        if (k < 128) return W_f[k * 128 + cc];
        if (k < 256) return U_f[(k - 128) * 128 + cc];
        return 0.0f;
    } else {
        int cc = col - 512;
        if (k < 128) return W_f[k * 128 + cc];
        if (k < 256) return 0.0f;
        return U_f[(k - 256) * 128 + cc];
    }
}

// ---------------- prep (round-5 verbatim) ----------------
#define TOT_INT (12 * 40 * 2 * 512)        // 491520
#define TOT_LEAF (4 * 24 * 2 * 512)        // 98304
#define ZBF_OFF (TOT_INT + TOT_LEAF)       // 589824
#define EPL_OFF (ZBF_OFF + 128)            // 589952
#define TOT_E 4096000
#define ZBP_OFF (EPL_OFF + TOT_E)          // 4685952
#define PREP_ALL (ZBP_OFF + 128)           // 4686080

__global__ __launch_bounds__(256) void prep_kernel(
    const float* __restrict__ W_iou, const float* __restrict__ W_f,
    const float* __restrict__ U_iou, const float* __restrict__ U_f,
    const float* __restrict__ E,
    u16* __restrict__ Bint, u16* __restrict__ Bleaf,
    u16* __restrict__ EH, u16* __restrict__ EL,
    u16* __restrict__ zbp, float* __restrict__ zbf, int do_planes)
{
    int idx = blockIdx.x * 256 + threadIdx.x;
    if (idx < TOT_INT) {
        int j = idx & 7, l = (idx >> 3) & 63, half = (idx >> 9) & 1;
        int rest = idx >> 10;
        int cfabs = rest % 40, kc = rest / 40;
        int colp = cfabs * 16 + (l & 15);
        int wc = colp / 160, q = colp - wc * 160;
        int g = q >> 5, j0 = 32 * wc + (q & 31);
        int origcol = (g < 3) ? g * 128 + j0 : ((g == 3) ? 384 + j0 : 512 + j0);
        int k = kc * 32 + (l >> 4) * 8 + j;
        float v = bval_int(k, origcol, W_iou, W_f, U_iou, U_f);
        u16 hi = f2bf(v);
        Bint[idx] = half ? f2bf(v - bf2f(hi)) : hi;
    } else if (idx < TOT_INT + TOT_LEAF) {
        int i2 = idx - TOT_INT;
        int j = i2 & 7, l = (i2 >> 3) & 63, half = (i2 >> 9) & 1;
        int rest = i2 >> 10;
        int cfabs = rest % 24, kc = rest / 24;
        int colp = cfabs * 16 + (l & 15);
        int wc = colp / 96, q = colp - wc * 96;
        int g = q >> 5, j0 = 32 * wc + (q & 31);
        int origcol = g * 128 + j0;
        int k = kc * 32 + (l >> 4) * 8 + j;
        float v = W_iou[k * 384 + origcol];
        u16 hi = f2bf(v);
        Bleaf[i2] = half ? f2bf(v - bf2f(hi)) : hi;
    } else if (idx < EPL_OFF) {
        zbf[idx - ZBF_OFF] = 0.0f;
    } else if (do_planes) {
        if (idx < ZBP_OFF) {
            int i3 = idx - EPL_OFF;
            float v = E[i3];
            u16 hi = f2bf(v);
            EH[i3] = hi;
            EL[i3] = f2bf(v - bf2f(hi));
        } else if (idx < PREP_ALL) {
            zbp[idx - ZBP_OFF] = 0;
        }
    }
}

// ---------------- fused level GEMM + LSTM cell: barrier-free, LDS-free ----------------
// 512 thr = 8 waves (2 row x 4 col). BM=64, BK=32. Wave tile 32 x (NCF*16).
// A: per-lane direct global loads of bf16 hi/lo planes (lane l: row=l&15, kgrp=l>>4).
// B: direct global->reg, pre-layouted per-(kc,wc,cf) 1KB lines, chunked NG at a time.
// No __syncthreads, no LDS, no manual vmcnt: waves free-run, HW hides latency.
template<int NKC, int NCFA, int NG, bool INTERNAL, bool PLANES>
__global__ __launch_bounds__(512, 2) void gemm_lvl(
    const int* __restrict__ x, const int* __restrict__ mask,
    const float* __restrict__ E,
    const u16* __restrict__ EH, const u16* __restrict__ zbp,
    const float* __restrict__ zbf,
    const u16* __restrict__ Bg,
    const float* __restrict__ b_iou_x, const float* __restrict__ b_f_x,
    const float* __restrict__ b_iou_h, const float* __restrict__ b_f_h,
    float* __restrict__ h, float* __restrict__ c,
    u16* __restrict__ hbH, int s0, int M)
{
    constexpr int NCF = 2 * NG;
    const int t = threadIdx.x;
    const int n0 = s0 + blockIdx.x * 64;
    const int lastn = s0 + M;
    const int l = t & 63, wid = t >> 6;
    const int wr = wid >> 2, wcq = wid & 3;
    const int lr = l & 15, lg = l >> 4;
    const int laneK = lg * 8;   // lg in [0,4): k-offset 0..24, +j<8 stays <32

    int nrA = n0 + 32 * wr + lr;
    int nrB = n0 + 32 * wr + 16 + lr;
    if (nrA >= lastn) nrA = s0;
    if (nrB >= lastn) nrB = s0;

    f32x4 acc[2][NCF];
    const f32x4 zzz = {0.0f, 0.0f, 0.0f, 0.0f};
#pragma unroll
    for (int rf = 0; rf < 2; ++rf)
#pragma unroll
        for (int cf = 0; cf < NCF; ++cf) acc[rf][cf] = zzz;

    auto body = [&](bfrag a0h, bfrag a0l, bfrag a1h, bfrag a1l, int kc) {
        const u16* bp = Bg + (size_t)(kc * NCFA + wcq * NCF) * 1024 + (size_t)l * 8;
#pragma unroll
        for (int ch = 0; ch < 2; ++ch) {
            bfrag bh[NG], bl[NG];
#pragma unroll
            for (int q = 0; q < NG; ++q) {
                bh[q] = *(const bfrag*)(bp + (ch * NG + q) * 1024);
                bl[q] = *(const bfrag*)(bp + (ch * NG + q) * 1024 + 512);
            }
#pragma unroll
            for (int q = 0; q < NG; ++q) {
                const int cf = ch * NG + q;
                acc[0][cf] = __builtin_amdgcn_mfma_f32_16x16x32_bf16(a0h, bh[q], acc[0][cf], 0, 0, 0);
                acc[1][cf] = __builtin_amdgcn_mfma_f32_16x16x32_bf16(a1h, bh[q], acc[1][cf], 0, 0, 0);
                acc[0][cf] = __builtin_amdgcn_mfma_f32_16x16x32_bf16(a0l, bh[q], acc[0][cf], 0, 0, 0);
                acc[1][cf] = __builtin_amdgcn_mfma_f32_16x16x32_bf16(a1l, bh[q], acc[1][cf], 0, 0, 0);
                acc[0][cf] = __builtin_amdgcn_mfma_f32_16x16x32_bf16(a0h, bl[q], acc[0][cf], 0, 0, 0);
                acc[1][cf] = __builtin_amdgcn_mfma_f32_16x16x32_bf16(a1h, bl[q], acc[1][cf], 0, 0, 0);
            }
        }
    };

    if constexpr (PLANES) {
        auto segP = [&](const u16* p0, int d0, const u16* p1, int d1, int kcBase) {
#pragma unroll 1
            for (int k4 = 0; k4 < 4; ++k4) {
                bfrag a0h = *(const bfrag*)(p0 + k4 * 32);
                bfrag a0l = *(const bfrag*)(p0 + k4 * 32 + d0);
                bfrag a1h = *(const bfrag*)(p1 + k4 * 32);
                bfrag a1l = *(const bfrag*)(p1 + k4 * 32 + d1);
                body(a0h, a0l, a1h, a1l, kcBase + k4);
            }
        };
        int mk0 = mask[nrA], mk1 = mask[nrB];
        const u16* pE0 = (mk0 ? EH + (size_t)x[nrA] * HS : zbp) + laneK;
        const u16* pE1 = (mk1 ? EH + (size_t)x[nrB] * HS : zbp) + laneK;
        int dE0 = mk0 ? DPLANE : 0;
        int dE1 = mk1 ? DPLANE : 0;
        segP(pE0, dE0, pE1, dE1, 0);
        if constexpr (INTERNAL) {
            const u16* pL0 = hbH + (size_t)(2 * nrA + 1) * HS + laneK;
            const u16* pL1 = hbH + (size_t)(2 * nrB + 1) * HS + laneK;
            segP(pL0, DHB, pL1, DHB, 4);
            const u16* pR0 = hbH + (size_t)(2 * nrA + 2) * HS + laneK;
            const u16* pR1 = hbH + (size_t)(2 * nrB + 2) * HS + laneK;
            segP(pR0, DHB, pR1, DHB, 8);
        }
    } else {
        auto cvt = [&](const float* p, bfrag& H, bfrag& L) {
            f32x4 v0 = *(const f32x4*)p;
            f32x4 v1 = *(const f32x4*)(p + 4);
#pragma unroll
            for (int j = 0; j < 4; ++j) {
                u32 u = __float_as_uint(v0[j]); u32 hu = u & 0xFFFF0000u;
                H[j] = (short)(hu >> 16);
                L[j] = (short)f2bf(v0[j] - __uint_as_float(hu));
            }
#pragma unroll
            for (int j = 0; j < 4; ++j) {
                u32 u = __float_as_uint(v1[j]); u32 hu = u & 0xFFFF0000u;
                H[4 + j] = (short)(hu >> 16);
                L[4 + j] = (short)f2bf(v1[j] - __uint_as_float(hu));
            }
        };
        auto segF = [&](const float* p0, const float* p1, int kcBase) {
#pragma unroll 1
            for (int k4 = 0; k4 < 4; ++k4) {
                bfrag a0h, a0l, a1h, a1l;
                cvt(p0 + k4 * 32, a0h, a0l);
                cvt(p1 + k4 * 32, a1h, a1l);
                body(a0h, a0l, a1h, a1l, kcBase + k4);
            }
        };
        const float* pE0 = (mask[nrA] ? E + (size_t)x[nrA] * HS : zbf) + laneK;
        const float* pE1 = (mask[nrB] ? E + (size_t)x[nrB] * HS : zbf) + laneK;
        segF(pE0, pE1, 0);
        if constexpr (INTERNAL) {
            segF(h + (size_t)(2 * nrA + 1) * HS + laneK, h + (size_t)(2 * nrB + 1) * HS + laneK, 4);
            segF(h + (size_t)(2 * nrA + 2) * HS + laneK, h + (size_t)(2 * nrB + 2) * HS + laneK, 8);
        }
    }

    // ---- register-local epilogue (round-5 verbatim) ----
    u16* hbL = hbH + DHB;
#pragma unroll
    for (int hi = 0; hi < 2; ++hi) {
        int j = 32 * wcq + 16 * hi + lr;
        float bix = b_iou_x[j], box = b_iou_x[HS + j], bux = b_iou_x[2 * HS + j];
        float bih = b_iou_h[j], boh = b_iou_h[HS + j], buh = b_iou_h[2 * HS + j];
        float bfx = 0.0f, bfh = 0.0f;
        if constexpr (INTERNAL) { bfx = b_f_x[j]; bfh = b_f_h[j]; }
#pragma unroll
        for (int rf = 0; rf < 2; ++rf) {
#pragma unroll
            for (int r = 0; r < 4; ++r) {
                int n = n0 + 32 * wr + 16 * rf + 4 * lg + r;
                if (n >= lastn) continue;
                float m = (float)mask[n];
                float iv = acc[rf][0 + hi][r] + m * bix + bih;
                float ov = acc[rf][2 + hi][r] + m * box + boh;
                float uv = acc[rf][4 + hi][r] + m * bux + buh;
                float cn;
                if constexpr (INTERNAL) {
                    float fl = acc[rf][6 + hi][r] + m * bfx + bfh;
                    float fr = acc[rf][8 + hi][r] + m * bfx + bfh;
                    float cl = c[(size_t)(2 * n + 1) * HS + j];
                    float cr = c[(size_t)(2 * n + 2) * HS + j];
                    cn = sigf(iv) * tanhfast(uv) + sigf(fl) * cl + sigf(fr) * cr;
                } else {
                    cn = sigf(iv) * tanhfast(uv);
                }
                float hn = sigf(ov) * tanhfast(cn);
                c[(size_t)n * HS + j] = cn;
                h[(size_t)n * HS + j] = hn;
                if constexpr (PLANES) {
                    u16 hh = f2bf(hn);
                    hbH[(size_t)n * HS + j] = hh;
                    hbL[(size_t)n * HS + j] = f2bf(hn - bf2f(hh));
                }
            }
        }
    }
}

extern "C" void kernel_launch(void* const* d_in, const int* in_sizes, int n_in,
                              void* d_out, int out_size, void* d_ws, size_t ws_size,
                              hipStream_t stream)
{
    const int*   x       = (const int*)d_in[0];
    const int*   mask    = (const int*)d_in[1];
    const float* E       = (const float*)d_in[2];
    const float* W_iou   = (const float*)d_in[3];
    const float* b_iou_x = (const float*)d_in[4];
    const float* W_f     = (const float*)d_in[5];
    const float* b_f_x   = (const float*)d_in[6];
    const float* U_iou   = (const float*)d_in[7];
    const float* b_iou_h = (const float*)d_in[8];
    const float* U_f     = (const float*)d_in[9];
    const float* b_f_h   = (const float*)d_in[10];

    float* h = (float*)d_out;
    char* ws = (char*)d_ws;

    u16*   Bint  = (u16*)(ws);                      // 983,040
    u16*   Bleaf = (u16*)(ws + 983040);             // 196,608 -> 1,179,648
    float* zbf   = (float*)(ws + 1179648);          // 512     -> 1,180,160

    const size_t NEED = 285998848ull;
    bool planes = ws_size >= NEED;

    if (planes) {
        u16*   EH  = (u16*)(ws + 1180160);           // 8,192,000  -> 9,372,160
        u16*   EL  = (u16*)(ws + 9372160);           // 8,192,000  -> 17,564,160  (EH + DPLANE)
        u16*   zbp = (u16*)(ws + 17564160);          // 256        -> 17,564,416
        float* c   = (float*)(ws + 17564416);        // 134,217,216 -> 151,781,632
        u16*   hbH = (u16*)(ws + 151781632);         // 67,108,608  -> 218,890,240
        // hbL = hbH + DHB                           // 67,108,608  -> 285,998,848

        prep_kernel<<<PREP_ALL / 256, 256, 0, stream>>>(
            W_iou, W_f, U_iou, U_f, E, Bint, Bleaf, EH, EL, zbp, zbf, 1);

        {   // leaves, lvl = 17: K=128 (4 kc), 384 cols
            int s0 = (1 << 17) - 1, M = 1 << 17;
            gemm_lvl<4, 24, 3, false, true><<<M / 64, 512, 0, stream>>>(
                x, mask, E, EH, zbp, zbf, Bleaf,
                b_iou_x, b_f_x, b_iou_h, b_f_h, h, c, hbH, s0, M);
        }
        for (int lvl = 16; lvl >= 0; --lvl) {
            int s0 = (1 << lvl) - 1, M = 1 << lvl;
            int blocks = (M + 63) / 64;
            gemm_lvl<12, 40, 5, true, true><<<blocks, 512, 0, stream>>>(
                x, mask, E, EH, zbp, zbf, Bint,
                b_iou_x, b_f_x, b_iou_h, b_f_h, h, c, hbH, s0, M);
        }
    } else {
        float* c = (float*)(ws + 1180160);
        prep_kernel<<<(EPL_OFF + 255) / 256, 256, 0, stream>>>(
            W_iou, W_f, U_iou, U_f, E, Bint, Bleaf, nullptr, nullptr, nullptr, zbf, 0);

        {   // leaves
            int s0 = (1 << 17) - 1, M = 1 << 17;
            gemm_lvl<4, 24, 3, false, false><<<M / 64, 512, 0, stream>>>(
                x, mask, E, nullptr, nullptr, zbf, Bleaf,
                b_iou_x, b_f_x, b_iou_h, b_f_h, h, c, nullptr, s0, M);
        }
        for (int lvl = 16; lvl >= 0; --lvl) {
            int s0 = (1 << lvl) - 1, M = 1 << lvl;
            int blocks = (M + 63) / 64;
            gemm_lvl<12, 40, 5, true, false><<<blocks, 512, 0, stream>>>(
                x, mask, E, nullptr, nullptr, zbf, Bint,
                b_iou_x, b_f_x, b_iou_h, b_f_h, h, c, nullptr, s0, M);
        }
    }
}

// Round 8
// 924.738 us; speedup vs baseline: 4.6703x; 1.0749x over previous
//
#include <hip/hip_runtime.h>
#include <math.h>

typedef unsigned short u16;
typedef unsigned int u32;
typedef float f32x4 __attribute__((ext_vector_type(4)));
typedef short bfrag __attribute__((ext_vector_type(8)));

#define HS 128
#define DPLANE 4096000      // EL - EH, u16 elements
#define DHB    33554304     // hbL - hbH, u16 elements (N*HS)

__device__ __forceinline__ float sigf(float x) { return 1.0f / (1.0f + __expf(-x)); }
__device__ __forceinline__ float tanhfast(float x) {
    float e = __expf(2.0f * x);
    return 1.0f - 2.0f / (e + 1.0f);
}
__device__ __forceinline__ u16 f2bf(float f) {
    u32 u = __float_as_uint(f);
    return (u16)((u + 0x7FFFu + ((u >> 16) & 1u)) >> 16);
}
__device__ __forceinline__ float bf2f(u16 h) { return __uint_as_float(((u32)h) << 16); }

// B' value: rows 0-127 emb:[W_iou|W_f|W_f], 128-255 hl:[U_iou|U_f|0], 256-383 hr:[U_iou|0|U_f]
__device__ __forceinline__ float bval_int(int k, int col,
    const float* W_iou, const float* W_f, const float* U_iou, const float* U_f)
{
    if (col < 384) {
        if (k < 128) return W_iou[k * 384 + col];
        if (k < 256) return U_iou[(k - 128) * 384 + col];
        return U_iou[(k - 256) * 384 + col];
    } else if (col < 512) {
        int cc = col - 384;
        if (k < 128) return W_f[k * 128 + cc];
        if (k < 256) return U_f[(k - 128) * 128 + cc];
        return 0.0f;
    } else {
        int cc = col - 512;
        if (k < 128) return W_f[k * 128 + cc];
        if (k < 256) return 0.0f;
        return U_f[(k - 256) * 128 + cc];
    }
}

// ---------------- prep (round-5 verbatim) ----------------
#define TOT_INT (12 * 40 * 2 * 512)        // 491520
#define TOT_LEAF (4 * 24 * 2 * 512)        // 98304
#define ZBF_OFF (TOT_INT + TOT_LEAF)       // 589824
#define EPL_OFF (ZBF_OFF + 128)            // 589952
#define TOT_E 4096000
#define ZBP_OFF (EPL_OFF + TOT_E)          // 4685952
#define PREP_ALL (ZBP_OFF + 128)           // 4686080

__global__ __launch_bounds__(256) void prep_kernel(
    const float* __restrict__ W_iou, const float* __restrict__ W_f,
    const float* __restrict__ U_iou, const float* __restrict__ U_f,
    const float* __restrict__ E,
    u16* __restrict__ Bint, u16* __restrict__ Bleaf,
    u16* __restrict__ EH, u16* __restrict__ EL,
    u16* __restrict__ zbp, float* __restrict__ zbf)
{
    int idx = blockIdx.x * 256 + threadIdx.x;
    if (idx < TOT_INT) {
        int j = idx & 7, l = (idx >> 3) & 63, half = (idx >> 9) & 1;
        int rest = idx >> 10;
        int cfabs = rest % 40, kc = rest / 40;
        int colp = cfabs * 16 + (l & 15);
        int wc = colp / 160, q = colp - wc * 160;
        int g = q >> 5, j0 = 32 * wc + (q & 31);
        int origcol = (g < 3) ? g * 128 + j0 : ((g == 3) ? 384 + j0 : 512 + j0);
        int k = kc * 32 + (l >> 4) * 8 + j;
        float v = bval_int(k, origcol, W_iou, W_f, U_iou, U_f);
        u16 hi = f2bf(v);
        Bint[idx] = half ? f2bf(v - bf2f(hi)) : hi;
    } else if (idx < TOT_INT + TOT_LEAF) {
        int i2 = idx - TOT_INT;
        int j = i2 & 7, l = (i2 >> 3) & 63, half = (i2 >> 9) & 1;
        int rest = i2 >> 10;
        int cfabs = rest % 24, kc = rest / 24;
        int colp = cfabs * 16 + (l & 15);
        int wc = colp / 96, q = colp - wc * 96;
        int g = q >> 5, j0 = 32 * wc + (q & 31);
        int origcol = g * 128 + j0;
        int k = kc * 32 + (l >> 4) * 8 + j;
        float v = W_iou[k * 384 + origcol];
        u16 hi = f2bf(v);
        Bleaf[i2] = half ? f2bf(v - bf2f(hi)) : hi;
    } else if (idx < EPL_OFF) {
        zbf[idx - ZBF_OFF] = 0.0f;
    } else if (idx < ZBP_OFF) {
        int i3 = idx - EPL_OFF;
        float v = E[i3];
        u16 hi = f2bf(v);
        EH[i3] = hi;
        EL[i3] = f2bf(v - bf2f(hi));
    } else if (idx < PREP_ALL) {
        zbp[idx - ZBP_OFF] = 0;
    }
}

// ---------------- one 64-row GEMM phase (r5 structure) ----------------
// MODE 0: leaf child  (K=128, A = E planes via DMA)
// MODE 1: internal child (K=384, A = E + grandchild hb planes via DMA)
// MODE 2: parent      (K=384, kc<4 E planes via DMA, kc>=4 child planes from ldsP)
template<int NKC, int NCFA, int NG, int MODE>
__device__ __forceinline__ void phase_gemm(
    f32x4 (&acc)[2][2 * NG],
    const int* __restrict__ x, const int* __restrict__ mask,
    const u16* __restrict__ EH, const u16* __restrict__ zbp,
    const u16* __restrict__ hbH,
    const u16* __restrict__ Bg,
    u16* ldsA, const u16* ldsP,
    int n0, int lastn, int t)
{
    constexpr int NCF = 2 * NG;
    constexpr int NB = 2 * NCF;
    const int l = t & 63, wid = t >> 6;
    const int wr = wid >> 2, wcq = wid & 3;
    const int lr = l & 15, lg = l >> 4;

    // staging source precompute (r5 verbatim; ns always < N so loads are in-bounds)
    const u16 *ebp, *hb1p = nullptr, *hb2p = nullptr;
    {
        const int prow = t & 63, pk8 = ((t >> 6) & 3) * 8, pp = t >> 8;
        int ns = n0 + prow; if (ns >= lastn) ns = n0;
        const u16* Ep = pp ? (EH + DPLANE) : EH;
        ebp = (mask[ns] ? Ep + (size_t)x[ns] * HS : zbp) + pk8;
        if (MODE == 1) {
            const u16* hbp = pp ? (hbH + DHB) : hbH;
            hb1p = hbp + (size_t)(2 * ns + 1) * HS + pk8;
            hb2p = hbp + (size_t)(2 * ns + 2) * HS + pk8;
        }
    }
    auto stageA = [&](int kc, int buf) {
        const u16* src;
        if (MODE == 1) {
            int seg = kc >> 2, ks = kc & 3;
            src = (seg == 0 ? ebp : (seg == 1 ? hb1p : hb2p)) + ks * 32;
        } else {
            src = ebp + (kc & 3) * 32;
        }
        __builtin_amdgcn_global_load_lds(
            (const __attribute__((address_space(1))) void*)src,
            (__attribute__((address_space(3))) void*)(ldsA + buf * 4096 + t * 8), 16, 0, 0);
    };

    stageA(0, 0);
    stageA(1 < NKC - 1 ? 1 : NKC - 1, 1);

#pragma unroll 1
    for (int kc = 0; kc < NKC; ++kc) {
        bfrag bh[NCF], bl[NCF];
        const u16* bp = Bg + ((size_t)(kc * NCFA + wcq * NCF) * 2) * 512 + (size_t)l * 8;
#pragma unroll
        for (int cf = 0; cf < NCF; ++cf) {
            bh[cf] = *(const bfrag*)(bp + (size_t)cf * 1024);
            bl[cf] = *(const bfrag*)(bp + (size_t)cf * 1024 + 512);
        }
        // retire A(kc); extra older ops (stores/dups) only make this stricter
        asm volatile("s_waitcnt vmcnt(%0)" :: "i"(NB + 1) : "memory");
        __builtin_amdgcn_s_barrier();
        asm volatile("" ::: "memory");
        if (MODE == 2) {
            if (kc < 2) stageA(kc + 2, (kc + 2) % 3);
        } else {
            int kn = kc + 2; if (kn > NKC - 1) kn = NKC - 1;
            stageA(kn, (kc + 2) % 3);
        }

        bfrag ah[2], al[2];
        if (MODE == 2 && kc >= 4) {
            const int seg = (kc - 4) >> 2;              // 0 = hl, 1 = hr
            const int kk8 = ((kc - 4) & 3) * 4 + lg;
#pragma unroll
            for (int rf = 0; rf < 2; ++rf) {
                int arow = 32 * wr + 16 * rf + lr;
                ah[rf] = *(const bfrag*)(ldsP + ((size_t)kk8 * 128 + seg * 64 + arow) * 8);
                al[rf] = *(const bfrag*)(ldsP + ((size_t)(16 + kk8) * 128 + seg * 64 + arow) * 8);
            }
        } else {
            const u16* ab = ldsA + (kc % 3) * 4096;
#pragma unroll
            for (int rf = 0; rf < 2; ++rf) {
                int arow = 32 * wr + 16 * rf + lr;
                ah[rf] = *(const bfrag*)(ab + ((size_t)lg * 64 + arow) * 8);
                al[rf] = *(const bfrag*)(ab + ((size_t)(4 + lg) * 64 + arow) * 8);
            }
        }

#pragma unroll
        for (int cf = 0; cf < NCF; ++cf) {
            acc[0][cf] = __builtin_amdgcn_mfma_f32_16x16x32_bf16(ah[0], bh[cf], acc[0][cf], 0, 0, 0);
            acc[1][cf] = __builtin_amdgcn_mfma_f32_16x16x32_bf16(ah[1], bh[cf], acc[1][cf], 0, 0, 0);
            acc[0][cf] = __builtin_amdgcn_mfma_f32_16x16x32_bf16(al[0], bh[cf], acc[0][cf], 0, 0, 0);
            acc[1][cf] = __builtin_amdgcn_mfma_f32_16x16x32_bf16(al[1], bh[cf], acc[1][cf], 0, 0, 0);
            acc[0][cf] = __builtin_amdgcn_mfma_f32_16x16x32_bf16(ah[0], bl[cf], acc[0][cf], 0, 0, 0);
            acc[1][cf] = __builtin_amdgcn_mfma_f32_16x16x32_bf16(ah[1], bl[cf], acc[1][cf], 0, 0, 0);
        }
    }
}

// ---------------- child epilogue: h -> HBM; planes + c -> LDS ----------------
template<int NG, bool LEAF>
__device__ __forceinline__ void child_epilogue(
    f32x4 (&acc)[2][2 * NG],
    const int* __restrict__ mask,
    const float* __restrict__ b_iou_x, const float* __restrict__ b_f_x,
    const float* __restrict__ b_iou_h, const float* __restrict__ b_f_h,
    float* __restrict__ h, const float* __restrict__ c,
    u16* ldsP, float* ldsC,
    int n0, int lastn, int oBase, int t)
{
    const int l = t & 63, wid = t >> 6;
    const int wr = wid >> 2, wcq = wid & 3;
    const int lr = l & 15, lg = l >> 4;
#pragma unroll
    for (int hi = 0; hi < 2; ++hi) {
        int j = 32 * wcq + 16 * hi + lr;
        float bix = b_iou_x[j], box = b_iou_x[HS + j], bux = b_iou_x[2 * HS + j];
        float bih = b_iou_h[j], boh = b_iou_h[HS + j], buh = b_iou_h[2 * HS + j];
        float bfx = 0.0f, bfh = 0.0f;
        if constexpr (!LEAF) { bfx = b_f_x[j]; bfh = b_f_h[j]; }
#pragma unroll
        for (int rf = 0; rf < 2; ++rf) {
#pragma unroll
            for (int r = 0; r < 4; ++r) {
                int ctr = 32 * wr + 16 * rf + 4 * lg + r;
                int n = n0 + ctr;
                if (n >= lastn) continue;
                float m = (float)mask[n];
                float iv = acc[rf][0 + hi][r] + m * bix + bih;
                float ov = acc[rf][2 + hi][r] + m * box + boh;
                float uv = acc[rf][4 + hi][r] + m * bux + buh;
                float cn;
                if constexpr (!LEAF) {
                    float fl = acc[rf][6 + hi][r] + m * bfx + bfh;
                    float fr = acc[rf][8 + hi][r] + m * bfx + bfh;
                    float cl = c[(size_t)(2 * n + 1) * HS + j];
                    float cr = c[(size_t)(2 * n + 2) * HS + j];
                    cn = sigf(iv) * tanhfast(uv) + sigf(fl) * cl + sigf(fr) * cr;
                } else {
                    cn = sigf(iv) * tanhfast(uv);
                }
                float hn = sigf(ov) * tanhfast(cn);
                h[(size_t)n * HS + j] = hn;
                int o = oBase + ctr;
                int half = o & 1, slot = o >> 1;
                u16 hh = f2bf(hn);
                ldsP[((size_t)(j >> 3) * 128 + half * 64 + slot) * 8 + (j & 7)] = hh;
                ldsP[((size_t)(16 + (j >> 3)) * 128 + half * 64 + slot) * 8 + (j & 7)] = f2bf(hn - bf2f(hh));
                ldsC[o * 129 + j] = cn;
            }
        }
    }
}

// ---------------- parent epilogue: h, c, planes -> HBM; c_agg from LDS ----------------
__device__ __forceinline__ void parent_epilogue(
    f32x4 (&acc)[2][10],
    const int* __restrict__ mask,
    const float* __restrict__ b_iou_x, const float* __restrict__ b_f_x,
    const float* __restrict__ b_iou_h, const float* __restrict__ b_f_h,
    float* __restrict__ h, float* __restrict__ c, u16* __restrict__ hbH,
    const float* ldsC,
    int n0, int lastn, int t)
{
    u16* hbL = hbH + DHB;
    const int l = t & 63, wid = t >> 6;
    const int wr = wid >> 2, wcq = wid & 3;
    const int lr = l & 15, lg = l >> 4;
#pragma unroll
    for (int hi = 0; hi < 2; ++hi) {
        int j = 32 * wcq + 16 * hi + lr;
        float bix = b_iou_x[j], box = b_iou_x[HS + j], bux = b_iou_x[2 * HS + j];
        float bih = b_iou_h[j], boh = b_iou_h[HS + j], buh = b_iou_h[2 * HS + j];
        float bfx = b_f_x[j], bfh = b_f_h[j];
#pragma unroll
        for (int rf = 0; rf < 2; ++rf) {
#pragma unroll
            for (int r = 0; r < 4; ++r) {
                int ctr = 32 * wr + 16 * rf + 4 * lg + r;
                int n = n0 + ctr;
                if (n >= lastn) continue;
                float m = (float)mask[n];
                float iv = acc[rf][0 + hi][r] + m * bix + bih;
                float ov = acc[rf][2 + hi][r] + m * box + boh;
                float uv = acc[rf][4 + hi][r] + m * bux + buh;
                float fl = acc[rf][6 + hi][r] + m * bfx + bfh;
                float fr = acc[rf][8 + hi][r] + m * bfx + bfh;
                float cl = ldsC[(2 * ctr) * 129 + j];
                float cr = ldsC[(2 * ctr + 1) * 129 + j];
                float cn = sigf(iv) * tanhfast(uv) + sigf(fl) * cl + sigf(fr) * cr;
                float hn = sigf(ov) * tanhfast(cn);
                c[(size_t)n * HS + j] = cn;
                h[(size_t)n * HS + j] = hn;
                u16 hh = f2bf(hn);
                hbH[(size_t)n * HS + j] = hh;
                hbL[(size_t)n * HS + j] = f2bf(hn - bf2f(hh));
            }
        }
    }
}

// ---------------- fused (parent, child) level-pair kernel ----------------
template<bool LEAFCH>
__global__ __launch_bounds__(512, 2) void fused_pair(
    const int* __restrict__ x, const int* __restrict__ mask,
    const u16* __restrict__ EH, const u16* __restrict__ zbp,
    const u16* __restrict__ Bint, const u16* __restrict__ Bleaf,
    const float* __restrict__ b_iou_x, const float* __restrict__ b_f_x,
    const float* __restrict__ b_iou_h, const float* __restrict__ b_f_h,
    float* __restrict__ h, float* __restrict__ c, u16* __restrict__ hbH,
    int s0p, int Mp)
{
    __shared__ __align__(16) u16 ldsA[3 * 4096];        // 24 KB A staging
    __shared__ __align__(16) u16 ldsP[2 * 16 * 128 * 8];// 64 KB child planes (parent A-frag layout)
    __shared__ __align__(16) float ldsC[128 * 129];     // 66 KB child c (padded)
    const int t = threadIdx.x;
    const int p0 = s0p + blockIdx.x * 64;
    const int lastp = s0p + Mp;
    const int lastc = 2 * lastp + 1;

    constexpr int CNG = LEAFCH ? 3 : 5;
    const f32x4 zzz = {0.0f, 0.0f, 0.0f, 0.0f};

    {   // child half A (children rows [2p0+1, 2p0+65))
        f32x4 acc[2][2 * CNG];
#pragma unroll
        for (int rf = 0; rf < 2; ++rf)
#pragma unroll
            for (int cf = 0; cf < 2 * CNG; ++cf) acc[rf][cf] = zzz;
        phase_gemm<LEAFCH ? 4 : 12, LEAFCH ? 24 : 40, CNG, LEAFCH ? 0 : 1>(
            acc, x, mask, EH, zbp, hbH, LEAFCH ? Bleaf : Bint, ldsA, ldsP, 2 * p0 + 1, lastc, t);
        child_epilogue<CNG, LEAFCH>(acc, mask, b_iou_x, b_f_x, b_iou_h, b_f_h,
                                    h, c, ldsP, ldsC, 2 * p0 + 1, lastc, 0, t);
    }
    __syncthreads();
    {   // child half B (children rows [2p0+65, 2p0+129))
        f32x4 acc[2][2 * CNG];
#pragma unroll
        for (int rf = 0; rf < 2; ++rf)
#pragma unroll
            for (int cf = 0; cf < 2 * CNG; ++cf) acc[rf][cf] = zzz;
        phase_gemm<LEAFCH ? 4 : 12, LEAFCH ? 24 : 40, CNG, LEAFCH ? 0 : 1>(
            acc, x, mask, EH, zbp, hbH, LEAFCH ? Bleaf : Bint, ldsA, ldsP, 2 * p0 + 65, lastc, t);
        child_epilogue<CNG, LEAFCH>(acc, mask, b_iou_x, b_f_x, b_iou_h, b_f_h,
                                    h, c, ldsP, ldsC, 2 * p0 + 65, lastc, 64, t);
    }
    __syncthreads();
    {   // parent (rows [p0, p0+64))
        f32x4 acc[2][10];
#pragma unroll
        for (int rf = 0; rf < 2; ++rf)
#pragma unroll
            for (int cf = 0; cf < 10; ++cf) acc[rf][cf] = zzz;
        phase_gemm<12, 40, 5, 2>(acc, x, mask, EH, zbp, hbH, Bint, ldsA, ldsP, p0, lastp, t);
        parent_epilogue(acc, mask, b_iou_x, b_f_x, b_iou_h, b_f_h,
                        h, c, hbH, ldsC, p0, lastp, t);
    }
}

extern "C" void kernel_launch(void* const* d_in, const int* in_sizes, int n_in,
                              void* d_out, int out_size, void* d_ws, size_t ws_size,
                              hipStream_t stream)
{
    const int*   x       = (const int*)d_in[0];
    const int*   mask    = (const int*)d_in[1];
    const float* E       = (const float*)d_in[2];
    const float* W_iou   = (const float*)d_in[3];
    const float* b_iou_x = (const float*)d_in[4];
    const float* W_f     = (const float*)d_in[5];
    const float* b_f_x   = (const float*)d_in[6];
    const float* U_iou   = (const float*)d_in[7];
    const float* b_iou_h = (const float*)d_in[8];
    const float* U_f     = (const float*)d_in[9];
    const float* b_f_h   = (const float*)d_in[10];

    float* h = (float*)d_out;
    char* ws = (char*)d_ws;

    u16*   Bint  = (u16*)(ws);                      // 983,040
    u16*   Bleaf = (u16*)(ws + 983040);             // 196,608 -> 1,179,648
    float* zbf   = (float*)(ws + 1179648);          // 512     -> 1,180,160
    u16*   EH    = (u16*)(ws + 1180160);            // 8,192,000  -> 9,372,160
    u16*   EL    = (u16*)(ws + 9372160);            // 8,192,000  -> 17,564,160 (EH + DPLANE)
    u16*   zbp   = (u16*)(ws + 17564160);           // 256        -> 17,564,416
    float* c     = (float*)(ws + 17564416);         // 134,217,216 -> 151,781,632
    u16*   hbH   = (u16*)(ws + 151781632);          // 2 x 67,108,608 -> 285,998,848 (hbL = hbH + DHB)

    prep_kernel<<<PREP_ALL / 256, 256, 0, stream>>>(
        W_iou, W_f, U_iou, U_f, E, Bint, Bleaf, EH, EL, zbp, zbf);

    // 9 fused (parent=lvl, children=lvl+1) pairs: (16,17), (14,15), ..., (0,1)
    for (int lvl = 16; lvl >= 0; lvl -= 2) {
        int s0p = (1 << lvl) - 1, Mp = 1 << lvl;
        int blocks = (Mp + 63) / 64;
        if (lvl == 16)
            fused_pair<true><<<blocks, 512, 0, stream>>>(
                x, mask, EH, zbp, Bint, Bleaf,
                b_iou_x, b_f_x, b_iou_h, b_f_h, h, c, hbH, s0p, Mp);
        else
            fused_pair<false><<<blocks, 512, 0, stream>>>(
                x, mask, EH, zbp, Bint, Bleaf,
                b_iou_x, b_f_x, b_iou_h, b_f_h, h, c, hbH, s0p, Mp);
    }
}

// Round 9
// 798.365 us; speedup vs baseline: 5.4095x; 1.1583x over previous
//
#include <hip/hip_runtime.h>
#include <math.h>

typedef unsigned short u16;
typedef unsigned int u32;
typedef float f32x4 __attribute__((ext_vector_type(4)));
typedef short bfrag __attribute__((ext_vector_type(8)));

#define HS 128
#define DPLANE 4096000      // EL - EH, u16 elements
#define DHB    33554304     // hbL - hbH, u16 elements (N*HS)

__device__ __forceinline__ float sigf(float x) { return 1.0f / (1.0f + __expf(-x)); }
__device__ __forceinline__ float tanhfast(float x) {
    float e = __expf(2.0f * x);
    return 1.0f - 2.0f / (e + 1.0f);
}
__device__ __forceinline__ u16 f2bf(float f) {
    u32 u = __float_as_uint(f);
    return (u16)((u + 0x7FFFu + ((u >> 16) & 1u)) >> 16);
}
__device__ __forceinline__ float bf2f(u16 h) { return __uint_as_float(((u32)h) << 16); }

template<int N> __device__ __forceinline__ void waitv() {
    asm volatile("s_waitcnt vmcnt(%0)" :: "i"(N) : "memory");
}

// B' value: rows 0-127 emb:[W_iou|W_f|W_f], 128-255 hl:[U_iou|U_f|0], 256-383 hr:[U_iou|0|U_f]
__device__ __forceinline__ float bval_int(int k, int col,
    const float* W_iou, const float* W_f, const float* U_iou, const float* U_f)
{
    if (col < 384) {
        if (k < 128) return W_iou[k * 384 + col];
        if (k < 256) return U_iou[(k - 128) * 384 + col];
        return U_iou[(k - 256) * 384 + col];
    } else if (col < 512) {
        int cc = col - 384;
        if (k < 128) return W_f[k * 128 + cc];
        if (k < 256) return U_f[(k - 128) * 128 + cc];
        return 0.0f;
    } else {
        int cc = col - 512;
        if (k < 128) return W_f[k * 128 + cc];
        if (k < 256) return 0.0f;
        return U_f[(k - 256) * 128 + cc];
    }
}

// ---------------- prep: B layout for 8-column-wave geometry ----------------
// idx = ((kc*NCFA + cfabs)*2 + half)*512 + l*8 + j8
// cfabs = wq*NCF + g ; lane lr -> col j = 16*wq + lr ; gate g ; k = kc*32 + (l>>4)*8 + j8
#define TOT_INT (12 * 40 * 2 * 512)        // 491520
#define TOT_LEAF (4 * 24 * 2 * 512)        // 98304
#define ZBF_OFF (TOT_INT + TOT_LEAF)       // 589824
#define EPL_OFF (ZBF_OFF + 128)            // 589952
#define TOT_E 4096000
#define ZBP_OFF (EPL_OFF + TOT_E)          // 4685952
#define PREP_ALL (ZBP_OFF + 128)           // 4686080

__global__ __launch_bounds__(256) void prep_kernel(
    const float* __restrict__ W_iou, const float* __restrict__ W_f,
    const float* __restrict__ U_iou, const float* __restrict__ U_f,
    const float* __restrict__ E,
    u16* __restrict__ Bint, u16* __restrict__ Bleaf,
    u16* __restrict__ EH, u16* __restrict__ EL,
    u16* __restrict__ zbp, float* __restrict__ zbf)
{
    int idx = blockIdx.x * 256 + threadIdx.x;
    if (idx < TOT_INT) {
        int j8 = idx & 7, l = (idx >> 3) & 63, half = (idx >> 9) & 1;
        int rest = idx >> 10;
        int cfabs = rest % 40, kc = rest / 40;
        int wq = cfabs / 5, g = cfabs % 5;
        int j = 16 * wq + (l & 15);
        int origcol = (g < 3) ? g * 128 + j : ((g == 3) ? 384 + j : 512 + j);
        int k = kc * 32 + (l >> 4) * 8 + j8;
        float v = bval_int(k, origcol, W_iou, W_f, U_iou, U_f);
        u16 hi = f2bf(v);
        Bint[idx] = half ? f2bf(v - bf2f(hi)) : hi;
    } else if (idx < TOT_INT + TOT_LEAF) {
        int i2 = idx - TOT_INT;
        int j8 = i2 & 7, l = (i2 >> 3) & 63, half = (i2 >> 9) & 1;
        int rest = i2 >> 10;
        int cfabs = rest % 24, kc = rest / 24;
        int wq = cfabs / 3, g = cfabs % 3;
        int origcol = g * 128 + 16 * wq + (l & 15);
        int k = kc * 32 + (l >> 4) * 8 + j8;
        float v = W_iou[k * 384 + origcol];
        u16 hi = f2bf(v);
        Bleaf[i2] = half ? f2bf(v - bf2f(hi)) : hi;
    } else if (idx < EPL_OFF) {
        zbf[idx - ZBF_OFF] = 0.0f;
    } else if (idx < ZBP_OFF) {
        int i3 = idx - EPL_OFF;
        float v = E[i3];
        u16 hi = f2bf(v);
        EH[i3] = hi;
        EL[i3] = f2bf(v - bf2f(hi));
    } else if (idx < PREP_ALL) {
        zbp[idx - ZBP_OFF] = 0;
    }
}

// ---------------- one 64-row GEMM phase, B-prefetch pipelined ----------------
// 8 waves, each: all 64 rows x NCF*16 cols (wave wq owns cols 16wq..16wq+15 of each gate).
// MODE 0: leaf child (K=128) | MODE 1: internal child (K=384) | MODE 2: parent
// (K=384; kc<4 from A-DMA, kc>=4 child planes from ldsP).
template<int NKC, int NCFA, int NCF, int MODE>
__device__ __forceinline__ void phase_gemm(
    f32x4 (&acc)[4][NCF],
    const int* __restrict__ x, const int* __restrict__ mask,
    const u16* __restrict__ EH, const u16* __restrict__ zbp,
    const u16* __restrict__ hbH,
    const u16* __restrict__ Bg,
    u16* ldsA, const u16* ldsP,
    int n0, int lastn, int t)
{
    constexpr int NB = 2 * NCF;
    const int l = t & 63, wq = t >> 6;
    const int lr = l & 15, lg = l >> 4;

    // staging source precompute (no address math / scalar loads inside K-loop)
    const u16 *ebp, *hb1p = nullptr, *hb2p = nullptr;
    {
        const int prow = t & 63, pk8 = ((t >> 6) & 3) * 8, pp = t >> 8;
        int ns = n0 + prow; if (ns >= lastn) ns = n0;
        const u16* Ep = pp ? (EH + DPLANE) : EH;
        ebp = (mask[ns] ? Ep + (size_t)x[ns] * HS : zbp) + pk8;
        if (MODE == 1) {
            const u16* hbp = pp ? (hbH + DHB) : hbH;
            hb1p = hbp + (size_t)(2 * ns + 1) * HS + pk8;
            hb2p = hbp + (size_t)(2 * ns + 2) * HS + pk8;
        }
    }
    auto stageA = [&](int kc, int buf) {
        const u16* src;
        if (MODE == 1) {
            int seg = kc >> 2, ks = kc & 3;
            src = (seg == 0 ? ebp : (seg == 1 ? hb1p : hb2p)) + ks * 32;
        } else {
            src = ebp + (kc & 3) * 32;
        }
        __builtin_amdgcn_global_load_lds(
            (const __attribute__((address_space(1))) void*)src,
            (__attribute__((address_space(3))) void*)(ldsA + buf * 4096 + t * 8), 16, 0, 0);
    };
    const u16* bbase = Bg + (size_t)(wq * NCF) * 1024 + (size_t)l * 8;
    auto loadB = [&](int kc, bfrag (&bh)[NCF], bfrag (&bl)[NCF]) {
        const u16* bp = bbase + (size_t)kc * ((size_t)NCFA * 1024);
#pragma unroll
        for (int cf = 0; cf < NCF; ++cf) {
            bh[cf] = *(const bfrag*)(bp + (size_t)cf * 1024);
            bl[cf] = *(const bfrag*)(bp + (size_t)cf * 1024 + 512);
        }
    };
    auto compute = [&](int kk, bfrag (&bh)[NCF], bfrag (&bl)[NCF]) {
        bfrag ah[4], al[4];
        if (MODE == 2 && kk >= 4) {
            const int seg = (kk - 4) >> 2;
            const int kk8 = ((kk - 4) & 3) * 4 + lg;
#pragma unroll
            for (int rf = 0; rf < 4; ++rf) {
                int arow = 16 * rf + lr;
                ah[rf] = *(const bfrag*)(ldsP + ((size_t)kk8 * 128 + seg * 64 + arow) * 8);
                al[rf] = *(const bfrag*)(ldsP + ((size_t)(16 + kk8) * 128 + seg * 64 + arow) * 8);
            }
        } else {
            const u16* ab = ldsA + (kk % 3) * 4096;
#pragma unroll
            for (int rf = 0; rf < 4; ++rf) {
                int arow = 16 * rf + lr;
                ah[rf] = *(const bfrag*)(ab + ((size_t)lg * 64 + arow) * 8);
                al[rf] = *(const bfrag*)(ab + ((size_t)(4 + lg) * 64 + arow) * 8);
            }
        }
#pragma unroll
        for (int cf = 0; cf < NCF; ++cf) {
#pragma unroll
            for (int rf = 0; rf < 4; ++rf)
                acc[rf][cf] = __builtin_amdgcn_mfma_f32_16x16x32_bf16(ah[rf], bh[cf], acc[rf][cf], 0, 0, 0);
#pragma unroll
            for (int rf = 0; rf < 4; ++rf)
                acc[rf][cf] = __builtin_amdgcn_mfma_f32_16x16x32_bf16(al[rf], bh[cf], acc[rf][cf], 0, 0, 0);
#pragma unroll
            for (int rf = 0; rf < 4; ++rf)
                acc[rf][cf] = __builtin_amdgcn_mfma_f32_16x16x32_bf16(ah[rf], bl[cf], acc[rf][cf], 0, 0, 0);
        }
    };

    bfrag bhA[NCF], blA[NCF], bhB[NCF], blB[NCF];
    stageA(0, 0);
    loadB(0, bhA, blA);
    stageA(1, 1);

#pragma unroll 1
    for (int kc = 0; kc < NKC; kc += 2) {
        // ---- half A: step kc (B in bhA/blA, prefetched last half) ----
        loadB(kc + 1, bhB, blB);
        if constexpr (MODE == 2) { if (kc <= 2) waitv<NB + 1>(); else waitv<NB>(); }
        else waitv<NB + 1>();
        __builtin_amdgcn_s_barrier();
        asm volatile("" ::: "memory");
        if constexpr (MODE == 2) { if (kc + 2 < 4) stageA(kc + 2, (kc + 2) % 3); }
        else                     { if (kc + 2 <= NKC - 1) stageA(kc + 2, (kc + 2) % 3); }
        compute(kc, bhA, blA);

        // ---- half B: step kc+1 ----
        { int kn = kc + 2; if (kn > NKC - 1) kn = NKC - 1; loadB(kn, bhA, blA); }
        if constexpr (MODE == 2) { if (kc == 0) waitv<NB + 1>(); else waitv<NB>(); }
        else { if (kc == NKC - 2) waitv<NB>(); else waitv<NB + 1>(); }
        __builtin_amdgcn_s_barrier();
        asm volatile("" ::: "memory");
        if constexpr (MODE == 2) { if (kc + 3 < 4) stageA(kc + 3, (kc + 3) % 3); }
        else                     { if (kc + 3 <= NKC - 1) stageA(kc + 3, (kc + 3) % 3); }
        compute(kc + 1, bhB, blB);
    }
}

// ---------------- child epilogue: h -> HBM; planes + c -> LDS ----------------
template<int NCF, bool LEAF>
__device__ __forceinline__ void child_epilogue(
    f32x4 (&acc)[4][NCF],
    const int* __restrict__ mask,
    const float* __restrict__ b_iou_x, const float* __restrict__ b_f_x,
    const float* __restrict__ b_iou_h, const float* __restrict__ b_f_h,
    float* __restrict__ h, const float* __restrict__ c,
    u16* ldsP, float* ldsC,
    int n0, int lastn, int oBase, int t)
{
    const int l = t & 63, wq = t >> 6, lr = l & 15, lg = l >> 4;
    const int j = 16 * wq + lr;
    float bix = b_iou_x[j], box = b_iou_x[HS + j], bux = b_iou_x[2 * HS + j];
    float bih = b_iou_h[j], boh = b_iou_h[HS + j], buh = b_iou_h[2 * HS + j];
    float bfx = 0.0f, bfh = 0.0f;
    if constexpr (!LEAF) { bfx = b_f_x[j]; bfh = b_f_h[j]; }
#pragma unroll
    for (int rf = 0; rf < 4; ++rf) {
#pragma unroll
        for (int r = 0; r < 4; ++r) {
            int ctr = 16 * rf + 4 * lg + r;
            int n = n0 + ctr;
            if (n >= lastn) continue;
            float m = (float)mask[n];
            float iv = acc[rf][0][r] + m * bix + bih;
            float ov = acc[rf][1][r] + m * box + boh;
            float uv = acc[rf][2][r] + m * bux + buh;
            float cn;
            if constexpr (!LEAF) {
                float fl = acc[rf][3][r] + m * bfx + bfh;
                float fr = acc[rf][4][r] + m * bfx + bfh;
                float cl = c[(size_t)(2 * n + 1) * HS + j];
                float cr = c[(size_t)(2 * n + 2) * HS + j];
                cn = sigf(iv) * tanhfast(uv) + sigf(fl) * cl + sigf(fr) * cr;
            } else {
                cn = sigf(iv) * tanhfast(uv);
            }
            float hn = sigf(ov) * tanhfast(cn);
            h[(size_t)n * HS + j] = hn;
            int o = oBase + ctr;
            int half = o & 1, slot = o >> 1;
            u16 hh = f2bf(hn);
            ldsP[((size_t)(j >> 3) * 128 + half * 64 + slot) * 8 + (j & 7)] = hh;
            ldsP[((size_t)(16 + (j >> 3)) * 128 + half * 64 + slot) * 8 + (j & 7)] = f2bf(hn - bf2f(hh));
            ldsC[o * 129 + j] = cn;
        }
    }
}

// ---------------- parent epilogue: h, c, planes -> HBM; c_agg from LDS ----------------
__device__ __forceinline__ void parent_epilogue(
    f32x4 (&acc)[4][5],
    const int* __restrict__ mask,
    const float* __restrict__ b_iou_x, const float* __restrict__ b_f_x,
    const float* __restrict__ b_iou_h, const float* __restrict__ b_f_h,
    float* __restrict__ h, float* __restrict__ c, u16* __restrict__ hbH,
    const float* ldsC,
    int n0, int lastn, int t)
{
    u16* hbL = hbH + DHB;
    const int l = t & 63, wq = t >> 6, lr = l & 15, lg = l >> 4;
    const int j = 16 * wq + lr;
    float bix = b_iou_x[j], box = b_iou_x[HS + j], bux = b_iou_x[2 * HS + j];
    float bih = b_iou_h[j], boh = b_iou_h[HS + j], buh = b_iou_h[2 * HS + j];
    float bfx = b_f_x[j], bfh = b_f_h[j];
#pragma unroll
    for (int rf = 0; rf < 4; ++rf) {
#pragma unroll
        for (int r = 0; r < 4; ++r) {
            int ctr = 16 * rf + 4 * lg + r;
            int n = n0 + ctr;
            if (n >= lastn) continue;
            float m = (float)mask[n];
            float iv = acc[rf][0][r] + m * bix + bih;
            float ov = acc[rf][1][r] + m * box + boh;
            float uv = acc[rf][2][r] + m * bux + buh;
            float fl = acc[rf][3][r] + m * bfx + bfh;
            float fr = acc[rf][4][r] + m * bfx + bfh;
            float cl = ldsC[(2 * ctr) * 129 + j];
            float cr = ldsC[(2 * ctr + 1) * 129 + j];
            float cn = sigf(iv) * tanhfast(uv) + sigf(fl) * cl + sigf(fr) * cr;
            float hn = sigf(ov) * tanhfast(cn);
            c[(size_t)n * HS + j] = cn;
            h[(size_t)n * HS + j] = hn;
            u16 hh = f2bf(hn);
            hbH[(size_t)n * HS + j] = hh;
            hbL[(size_t)n * HS + j] = f2bf(hn - bf2f(hh));
        }
    }
}

// ---------------- fused (parent, child) level-pair kernel ----------------
template<bool LEAFCH>
__global__ __launch_bounds__(512, 2) void fused_pair(
    const int* __restrict__ x, const int* __restrict__ mask,
    const u16* __restrict__ EH, const u16* __restrict__ zbp,
    const u16* __restrict__ Bint, const u16* __restrict__ Bleaf,
    const float* __restrict__ b_iou_x, const float* __restrict__ b_f_x,
    const float* __restrict__ b_iou_h, const float* __restrict__ b_f_h,
    float* __restrict__ h, float* __restrict__ c, u16* __restrict__ hbH,
    int s0p, int Mp)
{
    __shared__ __align__(16) u16 ldsA[3 * 4096];         // 24 KB A staging
    __shared__ __align__(16) u16 ldsP[2 * 16 * 128 * 8]; // 64 KB child planes
    __shared__ __align__(16) float ldsC[128 * 129];      // 66 KB child c (padded)
    const int t = threadIdx.x;
    const int p0 = s0p + blockIdx.x * 64;
    const int lastp = s0p + Mp;
    const int lastc = 2 * lastp + 1;

    constexpr int CNCF = LEAFCH ? 3 : 5;
    const f32x4 zzz = {0.0f, 0.0f, 0.0f, 0.0f};

    {   // child half A (children rows [2p0+1, 2p0+65))
        f32x4 acc[4][CNCF];
#pragma unroll
        for (int rf = 0; rf < 4; ++rf)
#pragma unroll
            for (int cf = 0; cf < CNCF; ++cf) acc[rf][cf] = zzz;
        phase_gemm<LEAFCH ? 4 : 12, LEAFCH ? 24 : 40, CNCF, LEAFCH ? 0 : 1>(
            acc, x, mask, EH, zbp, hbH, LEAFCH ? Bleaf : Bint, ldsA, ldsP, 2 * p0 + 1, lastc, t);
        child_epilogue<CNCF, LEAFCH>(acc, mask, b_iou_x, b_f_x, b_iou_h, b_f_h,
                                     h, c, ldsP, ldsC, 2 * p0 + 1, lastc, 0, t);
    }
    __syncthreads();
    {   // child half B (children rows [2p0+65, 2p0+129))
        f32x4 acc[4][CNCF];
#pragma unroll
        for (int rf = 0; rf < 4; ++rf)
#pragma unroll
            for (int cf = 0; cf < CNCF; ++cf) acc[rf][cf] = zzz;
        phase_gemm<LEAFCH ? 4 : 12, LEAFCH ? 24 : 40, CNCF, LEAFCH ? 0 : 1>(
            acc, x, mask, EH, zbp, hbH, LEAFCH ? Bleaf : Bint, ldsA, ldsP, 2 * p0 + 65, lastc, t);
        child_epilogue<CNCF, LEAFCH>(acc, mask, b_iou_x, b_f_x, b_iou_h, b_f_h,
                                     h, c, ldsP, ldsC, 2 * p0 + 65, lastc, 64, t);
    }
    __syncthreads();
    {   // parent (rows [p0, p0+64))
        f32x4 acc[4][5];
#pragma unroll
        for (int rf = 0; rf < 4; ++rf)
#pragma unroll
            for (int cf = 0; cf < 5; ++cf) acc[rf][cf] = zzz;
        phase_gemm<12, 40, 5, 2>(acc, x, mask, EH, zbp, hbH, Bint, ldsA, ldsP, p0, lastp, t);
        parent_epilogue(acc, mask, b_iou_x, b_f_x, b_iou_h, b_f_h,
                        h, c, hbH, ldsC, p0, lastp, t);
    }
}

extern "C" void kernel_launch(void* const* d_in, const int* in_sizes, int n_in,
                              void* d_out, int out_size, void* d_ws, size_t ws_size,
                              hipStream_t stream)
{
    const int*   x       = (const int*)d_in[0];
    const int*   mask    = (const int*)d_in[1];
    const float* E       = (const float*)d_in[2];
    const float* W_iou   = (const float*)d_in[3];
    const float* b_iou_x = (const float*)d_in[4];
    const float* W_f     = (const float*)d_in[5];
    const float* b_f_x   = (const float*)d_in[6];
    const float* U_iou   = (const float*)d_in[7];
    const float* b_iou_h = (const float*)d_in[8];
    const float* U_f     = (const float*)d_in[9];
    const float* b_f_h   = (const float*)d_in[10];

    float* h = (float*)d_out;
    char* ws = (char*)d_ws;

    u16*   Bint  = (u16*)(ws);                      // 983,040
    u16*   Bleaf = (u16*)(ws + 983040);             // 196,608 -> 1,179,648
    float* zbf   = (float*)(ws + 1179648);          // 512     -> 1,180,160
    u16*   EH    = (u16*)(ws + 1180160);            // 8,192,000  -> 9,372,160
    u16*   EL    = (u16*)(ws + 9372160);            // 8,192,000  -> 17,564,160 (EH + DPLANE)
    u16*   zbp   = (u16*)(ws + 17564160);           // 256        -> 17,564,416
    float* c     = (float*)(ws + 17564416);         // 134,217,216 -> 151,781,632
    u16*   hbH   = (u16*)(ws + 151781632);          // 2 x 67,108,608 -> 285,998,848 (hbL = hbH + DHB)

    prep_kernel<<<PREP_ALL / 256, 256, 0, stream>>>(
        W_iou, W_f, U_iou, U_f, E, Bint, Bleaf, EH, EL, zbp, zbf);

    // 9 fused (parent=lvl, children=lvl+1) pairs: (16,17), (14,15), ..., (0,1)
    for (int lvl = 16; lvl >= 0; lvl -= 2) {
        int s0p = (1 << lvl) - 1, Mp = 1 << lvl;
        int blocks = (Mp + 63) / 64;
        if (lvl == 16)
            fused_pair<true><<<blocks, 512, 0, stream>>>(
                x, mask, EH, zbp, Bint, Bleaf,
                b_iou_x, b_f_x, b_iou_h, b_f_h, h, c, hbH, s0p, Mp);
        else
            fused_pair<false><<<blocks, 512, 0, stream>>>(
                x, mask, EH, zbp, Bint, Bleaf,
                b_iou_x, b_f_x, b_iou_h, b_f_h, h, c, hbH, s0p, Mp);
    }
}

// Round 10
// 687.868 us; speedup vs baseline: 6.2785x; 1.1606x over previous
//
#include <hip/hip_runtime.h>
#include <math.h>

typedef unsigned short u16;
typedef unsigned int u32;
typedef float f32x4 __attribute__((ext_vector_type(4)));
typedef short bfrag __attribute__((ext_vector_type(8)));

#define HS 128
#define DPLANE 4096000      // EL - EH, u16 elements
#define DHB    33554304     // hbL - hbH, u16 elements (N*HS)

__device__ __forceinline__ float sigf(float x) { return 1.0f / (1.0f + __expf(-x)); }
__device__ __forceinline__ float tanhfast(float x) {
    float e = __expf(2.0f * x);
    return 1.0f - 2.0f / (e + 1.0f);
}
__device__ __forceinline__ u16 f2bf(float f) {
    u32 u = __float_as_uint(f);
    return (u16)((u + 0x7FFFu + ((u >> 16) & 1u)) >> 16);
}
__device__ __forceinline__ float bf2f(u16 h) { return __uint_as_float(((u32)h) << 16); }

template<int N> __device__ __forceinline__ void waitv() {
    asm volatile("s_waitcnt vmcnt(%0)" :: "i"(N) : "memory");
}

// B' value: rows 0-127 emb:[W_iou|W_f|W_f], 128-255 hl:[U_iou|U_f|0], 256-383 hr:[U_iou|0|U_f]
__device__ __forceinline__ float bval_int(int k, int col,
    const float* W_iou, const float* W_f, const float* U_iou, const float* U_f)
{
    if (col < 384) {
        if (k < 128) return W_iou[k * 384 + col];
        if (k < 256) return U_iou[(k - 128) * 384 + col];
        return U_iou[(k - 256) * 384 + col];
    } else if (col < 512) {
        int cc = col - 384;
        if (k < 128) return W_f[k * 128 + cc];
        if (k < 256) return U_f[(k - 128) * 128 + cc];
        return 0.0f;
    } else {
        int cc = col - 512;
        if (k < 128) return W_f[k * 128 + cc];
        if (k < 256) return 0.0f;
        return U_f[(k - 256) * 128 + cc];
    }
}

// ---------------- prep (round-9 verbatim; zbf slot doubles as barrier counters) ----------------
#define TOT_INT (12 * 40 * 2 * 512)        // 491520
#define TOT_LEAF (4 * 24 * 2 * 512)        // 98304
#define ZBF_OFF (TOT_INT + TOT_LEAF)       // 589824
#define EPL_OFF (ZBF_OFF + 128)            // 589952
#define TOT_E 4096000
#define ZBP_OFF (EPL_OFF + TOT_E)          // 4685952
#define PREP_ALL (ZBP_OFF + 128)           // 4686080

__global__ __launch_bounds__(256) void prep_kernel(
    const float* __restrict__ W_iou, const float* __restrict__ W_f,
    const float* __restrict__ U_iou, const float* __restrict__ U_f,
    const float* __restrict__ E,
    u16* __restrict__ Bint, u16* __restrict__ Bleaf,
    u16* __restrict__ EH, u16* __restrict__ EL,
    u16* __restrict__ zbp, float* __restrict__ zbf)
{
    int idx = blockIdx.x * 256 + threadIdx.x;
    if (idx < TOT_INT) {
        int j8 = idx & 7, l = (idx >> 3) & 63, half = (idx >> 9) & 1;
        int rest = idx >> 10;
        int cfabs = rest % 40, kc = rest / 40;
        int wq = cfabs / 5, g = cfabs % 5;
        int j = 16 * wq + (l & 15);
        int origcol = (g < 3) ? g * 128 + j : ((g == 3) ? 384 + j : 512 + j);
        int k = kc * 32 + (l >> 4) * 8 + j8;
        float v = bval_int(k, origcol, W_iou, W_f, U_iou, U_f);
        u16 hi = f2bf(v);
        Bint[idx] = half ? f2bf(v - bf2f(hi)) : hi;
    } else if (idx < TOT_INT + TOT_LEAF) {
        int i2 = idx - TOT_INT;
        int j8 = i2 & 7, l = (i2 >> 3) & 63, half = (i2 >> 9) & 1;
        int rest = i2 >> 10;
        int cfabs = rest % 24, kc = rest / 24;
        int wq = cfabs / 3, g = cfabs % 3;
        int origcol = g * 128 + 16 * wq + (l & 15);
        int k = kc * 32 + (l >> 4) * 8 + j8;
        float v = W_iou[k * 384 + origcol];
        u16 hi = f2bf(v);
        Bleaf[i2] = half ? f2bf(v - bf2f(hi)) : hi;
    } else if (idx < EPL_OFF) {
        zbf[idx - ZBF_OFF] = 0.0f;     // also zeroes the 16 grid-barrier counters
    } else if (idx < ZBP_OFF) {
        int i3 = idx - EPL_OFF;
        float v = E[i3];
        u16 hi = f2bf(v);
        EH[i3] = hi;
        EL[i3] = f2bf(v - bf2f(hi));
    } else if (idx < PREP_ALL) {
        zbp[idx - ZBP_OFF] = 0;
    }
}

// ---------------- one 64-row GEMM phase, B-prefetch pipelined (r9 verbatim) ----------------
// MODE 0: leaf child (K=128) | MODE 1: internal (K=384, A from planes via DMA) | MODE 2: parent
template<int NKC, int NCFA, int NCF, int MODE>
__device__ __forceinline__ void phase_gemm(
    f32x4 (&acc)[4][NCF],
    const int* __restrict__ x, const int* __restrict__ mask,
    const u16* __restrict__ EH, const u16* __restrict__ zbp,
    const u16* __restrict__ hbH,
    const u16* __restrict__ Bg,
    u16* ldsA, const u16* ldsP,
    int n0, int lastn, int t)
{
    constexpr int NB = 2 * NCF;
    const int l = t & 63, wq = t >> 6;
    const int lr = l & 15, lg = l >> 4;

    const u16 *ebp, *hb1p = nullptr, *hb2p = nullptr;
    {
        const int prow = t & 63, pk8 = ((t >> 6) & 3) * 8, pp = t >> 8;
        int ns = n0 + prow; if (ns >= lastn) ns = n0;
        const u16* Ep = pp ? (EH + DPLANE) : EH;
        ebp = (mask[ns] ? Ep + (size_t)x[ns] * HS : zbp) + pk8;
        if (MODE == 1) {
            const u16* hbp = pp ? (hbH + DHB) : hbH;
            hb1p = hbp + (size_t)(2 * ns + 1) * HS + pk8;
            hb2p = hbp + (size_t)(2 * ns + 2) * HS + pk8;
        }
    }
    auto stageA = [&](int kc, int buf) {
        const u16* src;
        if (MODE == 1) {
            int seg = kc >> 2, ks = kc & 3;
            src = (seg == 0 ? ebp : (seg == 1 ? hb1p : hb2p)) + ks * 32;
        } else {
            src = ebp + (kc & 3) * 32;
        }
        __builtin_amdgcn_global_load_lds(
            (const __attribute__((address_space(1))) void*)src,
            (__attribute__((address_space(3))) void*)(ldsA + buf * 4096 + t * 8), 16, 0, 0);
    };
    const u16* bbase = Bg + (size_t)(wq * NCF) * 1024 + (size_t)l * 8;
    auto loadB = [&](int kc, bfrag (&bh)[NCF], bfrag (&bl)[NCF]) {
        const u16* bp = bbase + (size_t)kc * ((size_t)NCFA * 1024);
#pragma unroll
        for (int cf = 0; cf < NCF; ++cf) {
            bh[cf] = *(const bfrag*)(bp + (size_t)cf * 1024);
            bl[cf] = *(const bfrag*)(bp + (size_t)cf * 1024 + 512);
        }
    };
    auto compute = [&](int kk, bfrag (&bh)[NCF], bfrag (&bl)[NCF]) {
        bfrag ah[4], al[4];
        if (MODE == 2 && kk >= 4) {
            const int seg = (kk - 4) >> 2;
            const int kk8 = ((kk - 4) & 3) * 4 + lg;
#pragma unroll
            for (int rf = 0; rf < 4; ++rf) {
                int arow = 16 * rf + lr;
                ah[rf] = *(const bfrag*)(ldsP + ((size_t)kk8 * 128 + seg * 64 + arow) * 8);
                al[rf] = *(const bfrag*)(ldsP + ((size_t)(16 + kk8) * 128 + seg * 64 + arow) * 8);
            }
        } else {
            const u16* ab = ldsA + (kk % 3) * 4096;
#pragma unroll
            for (int rf = 0; rf < 4; ++rf) {
                int arow = 16 * rf + lr;
                ah[rf] = *(const bfrag*)(ab + ((size_t)lg * 64 + arow) * 8);
                al[rf] = *(const bfrag*)(ab + ((size_t)(4 + lg) * 64 + arow) * 8);
            }
        }
#pragma unroll
        for (int cf = 0; cf < NCF; ++cf) {
#pragma unroll
            for (int rf = 0; rf < 4; ++rf)
                acc[rf][cf] = __builtin_amdgcn_mfma_f32_16x16x32_bf16(ah[rf], bh[cf], acc[rf][cf], 0, 0, 0);
#pragma unroll
            for (int rf = 0; rf < 4; ++rf)
                acc[rf][cf] = __builtin_amdgcn_mfma_f32_16x16x32_bf16(al[rf], bh[cf], acc[rf][cf], 0, 0, 0);
#pragma unroll
            for (int rf = 0; rf < 4; ++rf)
                acc[rf][cf] = __builtin_amdgcn_mfma_f32_16x16x32_bf16(ah[rf], bl[cf], acc[rf][cf], 0, 0, 0);
        }
    };

    bfrag bhA[NCF], blA[NCF], bhB[NCF], blB[NCF];
    stageA(0, 0);
    loadB(0, bhA, blA);
    stageA(1, 1);

#pragma unroll 1
    for (int kc = 0; kc < NKC; kc += 2) {
        loadB(kc + 1, bhB, blB);
        if constexpr (MODE == 2) { if (kc <= 2) waitv<NB + 1>(); else waitv<NB>(); }
        else waitv<NB + 1>();
        __builtin_amdgcn_s_barrier();
        asm volatile("" ::: "memory");
        if constexpr (MODE == 2) { if (kc + 2 < 4) stageA(kc + 2, (kc + 2) % 3); }
        else                     { if (kc + 2 <= NKC - 1) stageA(kc + 2, (kc + 2) % 3); }
        compute(kc, bhA, blA);

        { int kn = kc + 2; if (kn > NKC - 1) kn = NKC - 1; loadB(kn, bhA, blA); }
        if constexpr (MODE == 2) { if (kc == 0) waitv<NB + 1>(); else waitv<NB>(); }
        else { if (kc == NKC - 2) waitv<NB>(); else waitv<NB + 1>(); }
        __builtin_amdgcn_s_barrier();
        asm volatile("" ::: "memory");
        if constexpr (MODE == 2) { if (kc + 3 < 4) stageA(kc + 3, (kc + 3) % 3); }
        else                     { if (kc + 3 <= NKC - 1) stageA(kc + 3, (kc + 3) % 3); }
        compute(kc + 1, bhB, blB);
    }
}

// ---------------- child epilogue: h -> HBM; planes + c -> LDS (r9 verbatim) ----------------
template<int NCF, bool LEAF>
__device__ __forceinline__ void child_epilogue(
    f32x4 (&acc)[4][NCF],
    const int* __restrict__ mask,
    const float* __restrict__ b_iou_x, const float* __restrict__ b_f_x,
    const float* __restrict__ b_iou_h, const float* __restrict__ b_f_h,
    float* __restrict__ h, const float* __restrict__ c,
    u16* ldsP, float* ldsC,
    int n0, int lastn, int oBase, int t)
{
    const int l = t & 63, wq = t >> 6, lr = l & 15, lg = l >> 4;
    const int j = 16 * wq + lr;
    float bix = b_iou_x[j], box = b_iou_x[HS + j], bux = b_iou_x[2 * HS + j];
    float bih = b_iou_h[j], boh = b_iou_h[HS + j], buh = b_iou_h[2 * HS + j];
    float bfx = 0.0f, bfh = 0.0f;
    if constexpr (!LEAF) { bfx = b_f_x[j]; bfh = b_f_h[j]; }
#pragma unroll
    for (int rf = 0; rf < 4; ++rf) {
#pragma unroll
        for (int r = 0; r < 4; ++r) {
            int ctr = 16 * rf + 4 * lg + r;
            int n = n0 + ctr;
            if (n >= lastn) continue;
            float m = (float)mask[n];
            float iv = acc[rf][0][r] + m * bix + bih;
            float ov = acc[rf][1][r] + m * box + boh;
            float uv = acc[rf][2][r] + m * bux + buh;
            float cn;
            if constexpr (!LEAF) {
                float fl = acc[rf][3][r] + m * bfx + bfh;
                float fr = acc[rf][4][r] + m * bfx + bfh;
                float cl = c[(size_t)(2 * n + 1) * HS + j];
                float cr = c[(size_t)(2 * n + 2) * HS + j];
                cn = sigf(iv) * tanhfast(uv) + sigf(fl) * cl + sigf(fr) * cr;
            } else {
                cn = sigf(iv) * tanhfast(uv);
            }
            float hn = sigf(ov) * tanhfast(cn);
            h[(size_t)n * HS + j] = hn;
            int o = oBase + ctr;
            int half = o & 1, slot = o >> 1;
            u16 hh = f2bf(hn);
            ldsP[((size_t)(j >> 3) * 128 + half * 64 + slot) * 8 + (j & 7)] = hh;
            ldsP[((size_t)(16 + (j >> 3)) * 128 + half * 64 + slot) * 8 + (j & 7)] = f2bf(hn - bf2f(hh));
            ldsC[o * 129 + j] = cn;
        }
    }
}

// ---------------- parent epilogue: c_agg from LDS (r9 verbatim) ----------------
__device__ __forceinline__ void parent_epilogue(
    f32x4 (&acc)[4][5],
    const int* __restrict__ mask,
    const float* __restrict__ b_iou_x, const float* __restrict__ b_f_x,
    const float* __restrict__ b_iou_h, const float* __restrict__ b_f_h,
    float* __restrict__ h, float* __restrict__ c, u16* __restrict__ hbH,
    const float* ldsC,
    int n0, int lastn, int t)
{
    u16* hbL = hbH + DHB;
    const int l = t & 63, wq = t >> 6, lr = l & 15, lg = l >> 4;
    const int j = 16 * wq + lr;
    float bix = b_iou_x[j], box = b_iou_x[HS + j], bux = b_iou_x[2 * HS + j];
    float bih = b_iou_h[j], boh = b_iou_h[HS + j], buh = b_iou_h[2 * HS + j];
    float bfx = b_f_x[j], bfh = b_f_h[j];
#pragma unroll
    for (int rf = 0; rf < 4; ++rf) {
#pragma unroll
        for (int r = 0; r < 4; ++r) {
            int ctr = 16 * rf + 4 * lg + r;
            int n = n0 + ctr;
            if (n >= lastn) continue;
            float m = (float)mask[n];
            float iv = acc[rf][0][r] + m * bix + bih;
            float ov = acc[rf][1][r] + m * box + boh;
            float uv = acc[rf][2][r] + m * bux + buh;
            float fl = acc[rf][3][r] + m * bfx + bfh;
            float fr = acc[rf][4][r] + m * bfx + bfh;
            float cl = ldsC[(2 * ctr) * 129 + j];
            float cr = ldsC[(2 * ctr + 1) * 129 + j];
            float cn = sigf(iv) * tanhfast(uv) + sigf(fl) * cl + sigf(fr) * cr;
            float hn = sigf(ov) * tanhfast(cn);
            c[(size_t)n * HS + j] = cn;
            h[(size_t)n * HS + j] = hn;
            u16 hh = f2bf(hn);
            hbH[(size_t)n * HS + j] = hh;
            hbL[(size_t)n * HS + j] = f2bf(hn - bf2f(hh));
        }
    }
}

// ---------------- tail epilogue: like parent but c_agg from HBM ----------------
__device__ __forceinline__ void tail_epilogue(
    f32x4 (&acc)[4][5],
    const int* __restrict__ mask,
    const float* __restrict__ b_iou_x, const float* __restrict__ b_f_x,
    const float* __restrict__ b_iou_h, const float* __restrict__ b_f_h,
    float* __restrict__ h, float* __restrict__ c, u16* __restrict__ hbH,
    int n0, int lastn, int t)
{
    u16* hbL = hbH + DHB;
    const int l = t & 63, wq = t >> 6, lr = l & 15, lg = l >> 4;
    const int j = 16 * wq + lr;
    float bix = b_iou_x[j], box = b_iou_x[HS + j], bux = b_iou_x[2 * HS + j];
    float bih = b_iou_h[j], boh = b_iou_h[HS + j], buh = b_iou_h[2 * HS + j];
    float bfx = b_f_x[j], bfh = b_f_h[j];
#pragma unroll
    for (int rf = 0; rf < 4; ++rf) {
#pragma unroll
        for (int r = 0; r < 4; ++r) {
            int ctr = 16 * rf + 4 * lg + r;
            int n = n0 + ctr;
            if (n >= lastn) continue;
            float m = (float)mask[n];
            float iv = acc[rf][0][r] + m * bix + bih;
            float ov = acc[rf][1][r] + m * box + boh;
            float uv = acc[rf][2][r] + m * bux + buh;
            float fl = acc[rf][3][r] + m * bfx + bfh;
            float fr = acc[rf][4][r] + m * bfx + bfh;
            float cl = c[(size_t)(2 * n + 1) * HS + j];
            float cr = c[(size_t)(2 * n + 2) * HS + j];
            float cn = sigf(iv) * tanhfast(uv) + sigf(fl) * cl + sigf(fr) * cr;
            float hn = sigf(ov) * tanhfast(cn);
            c[(size_t)n * HS + j] = cn;
            h[(size_t)n * HS + j] = hn;
            u16 hh = f2bf(hn);
            hbH[(size_t)n * HS + j] = hh;
            hbL[(size_t)n * HS + j] = f2bf(hn - bf2f(hh));
        }
    }
}

// ---------------- fused (parent, child) level-pair kernel (r9 verbatim) ----------------
template<bool LEAFCH>
__global__ __launch_bounds__(512, 2) void fused_pair(
    const int* __restrict__ x, const int* __restrict__ mask,
    const u16* __restrict__ EH, const u16* __restrict__ zbp,
    const u16* __restrict__ Bint, const u16* __restrict__ Bleaf,
    const float* __restrict__ b_iou_x, const float* __restrict__ b_f_x,
    const float* __restrict__ b_iou_h, const float* __restrict__ b_f_h,
    float* __restrict__ h, float* __restrict__ c, u16* __restrict__ hbH,
    int s0p, int Mp)
{
    __shared__ __align__(16) u16 ldsA[3 * 4096];
    __shared__ __align__(16) u16 ldsP[2 * 16 * 128 * 8];
    __shared__ __align__(16) float ldsC[128 * 129];
    const int t = threadIdx.x;
    const int p0 = s0p + blockIdx.x * 64;
    const int lastp = s0p + Mp;
    const int lastc = 2 * lastp + 1;

    constexpr int CNCF = LEAFCH ? 3 : 5;
    const f32x4 zzz = {0.0f, 0.0f, 0.0f, 0.0f};

    {
        f32x4 acc[4][CNCF];
#pragma unroll
        for (int rf = 0; rf < 4; ++rf)
#pragma unroll
            for (int cf = 0; cf < CNCF; ++cf) acc[rf][cf] = zzz;
        phase_gemm<LEAFCH ? 4 : 12, LEAFCH ? 24 : 40, CNCF, LEAFCH ? 0 : 1>(
            acc, x, mask, EH, zbp, hbH, LEAFCH ? Bleaf : Bint, ldsA, ldsP, 2 * p0 + 1, lastc, t);
        child_epilogue<CNCF, LEAFCH>(acc, mask, b_iou_x, b_f_x, b_iou_h, b_f_h,
                                     h, c, ldsP, ldsC, 2 * p0 + 1, lastc, 0, t);
    }
    __syncthreads();
    {
        f32x4 acc[4][CNCF];
#pragma unroll
        for (int rf = 0; rf < 4; ++rf)
#pragma unroll
            for (int cf = 0; cf < CNCF; ++cf) acc[rf][cf] = zzz;
        phase_gemm<LEAFCH ? 4 : 12, LEAFCH ? 24 : 40, CNCF, LEAFCH ? 0 : 1>(
            acc, x, mask, EH, zbp, hbH, LEAFCH ? Bleaf : Bint, ldsA, ldsP, 2 * p0 + 65, lastc, t);
        child_epilogue<CNCF, LEAFCH>(acc, mask, b_iou_x, b_f_x, b_iou_h, b_f_h,
                                     h, c, ldsP, ldsC, 2 * p0 + 65, lastc, 64, t);
    }
    __syncthreads();
    {
        f32x4 acc[4][5];
#pragma unroll
        for (int rf = 0; rf < 4; ++rf)
#pragma unroll
            for (int cf = 0; cf < 5; ++cf) acc[rf][cf] = zzz;
        phase_gemm<12, 40, 5, 2>(acc, x, mask, EH, zbp, hbH, Bint, ldsA, ldsP, p0, lastp, t);
        parent_epilogue(acc, mask, b_iou_x, b_f_x, b_iou_h, b_f_h,
                        h, c, hbH, ldsC, p0, lastp, t);
    }
}

// ---------------- persistent tail kernel: levels 11..0, grid-barrier between levels ----------------
#define TAIL_BLOCKS 32

__device__ __forceinline__ void grid_barrier(u32* ctr, u32 target, int t) {
    __syncthreads();
    if (t == 0) {
        __threadfence();
        __hip_atomic_fetch_add(ctr, 1u, __ATOMIC_RELEASE, __HIP_MEMORY_SCOPE_AGENT);
        while (__hip_atomic_load(ctr, __ATOMIC_ACQUIRE, __HIP_MEMORY_SCOPE_AGENT) < target)
            __builtin_amdgcn_s_sleep(4);
        __threadfence();
    }
    __syncthreads();
}

__global__ __launch_bounds__(512, 2) void tail_kernel(
    const int* __restrict__ x, const int* __restrict__ mask,
    const u16* __restrict__ EH, const u16* __restrict__ zbp,
    const u16* __restrict__ Bint,
    const float* __restrict__ b_iou_x, const float* __restrict__ b_f_x,
    const float* __restrict__ b_iou_h, const float* __restrict__ b_f_h,
    float* __restrict__ h, float* __restrict__ c, u16* __restrict__ hbH,
    u32* __restrict__ bar)
{
    __shared__ __align__(16) u16 ldsA[3 * 4096];
    const int t = threadIdx.x;
    const f32x4 zzz = {0.0f, 0.0f, 0.0f, 0.0f};

#pragma unroll 1
    for (int lvl = 11; lvl >= 0; --lvl) {
        int s0 = (1 << lvl) - 1, M = 1 << lvl;
        int nb = (M + 63) >> 6;
        if ((int)blockIdx.x < nb) {
            int n0 = s0 + blockIdx.x * 64;
            int lastn = s0 + M;
            f32x4 acc[4][5];
#pragma unroll
            for (int rf = 0; rf < 4; ++rf)
#pragma unroll
                for (int cf = 0; cf < 5; ++cf) acc[rf][cf] = zzz;
            phase_gemm<12, 40, 5, 1>(acc, x, mask, EH, zbp, hbH, Bint,
                                     ldsA, nullptr, n0, lastn, t);
            tail_epilogue(acc, mask, b_iou_x, b_f_x, b_iou_h, b_f_h,
                          h, c, hbH, n0, lastn, t);
        }
        if (lvl > 0) grid_barrier(&bar[11 - lvl], TAIL_BLOCKS, t);
    }
}

extern "C" void kernel_launch(void* const* d_in, const int* in_sizes, int n_in,
                              void* d_out, int out_size, void* d_ws, size_t ws_size,
                              hipStream_t stream)
{
    const int*   x       = (const int*)d_in[0];
    const int*   mask    = (const int*)d_in[1];
    const float* E       = (const float*)d_in[2];
    const float* W_iou   = (const float*)d_in[3];
    const float* b_iou_x = (const float*)d_in[4];
    const float* W_f     = (const float*)d_in[5];
    const float* b_f_x   = (const float*)d_in[6];
    const float* U_iou   = (const float*)d_in[7];
    const float* b_iou_h = (const float*)d_in[8];
    const float* U_f     = (const float*)d_in[9];
    const float* b_f_h   = (const float*)d_in[10];

    float* h = (float*)d_out;
    char* ws = (char*)d_ws;

    u16*   Bint  = (u16*)(ws);                      // 983,040
    u16*   Bleaf = (u16*)(ws + 983040);             // 196,608 -> 1,179,648
    float* zbf   = (float*)(ws + 1179648);          // 512     -> 1,180,160 (barrier ctrs live here)
    u32*   bar   = (u32*)(ws + 1179648);            // 16 u32, zeroed by prep each launch
    u16*   EH    = (u16*)(ws + 1180160);            // 8,192,000  -> 9,372,160
    u16*   EL    = (u16*)(ws + 9372160);            // 8,192,000  -> 17,564,160 (EH + DPLANE)
    u16*   zbp   = (u16*)(ws + 17564160);           // 256        -> 17,564,416
    float* c     = (float*)(ws + 17564416);         // 134,217,216 -> 151,781,632
    u16*   hbH   = (u16*)(ws + 151781632);          // 2 x 67,108,608 -> 285,998,848 (hbL = hbH + DHB)

    prep_kernel<<<PREP_ALL / 256, 256, 0, stream>>>(
        W_iou, W_f, U_iou, U_f, E, Bint, Bleaf, EH, EL, zbp, zbf);

    // fused (parent, child) pairs for the big levels: (16,17), (14,15), (12,13)
    for (int lvl = 16; lvl >= 12; lvl -= 2) {
        int s0p = (1 << lvl) - 1, Mp = 1 << lvl;
        int blocks = (Mp + 63) / 64;
        if (lvl == 16)
            fused_pair<true><<<blocks, 512, 0, stream>>>(
                x, mask, EH, zbp, Bint, Bleaf,
                b_iou_x, b_f_x, b_iou_h, b_f_h, h, c, hbH, s0p, Mp);
        else
            fused_pair<false><<<blocks, 512, 0, stream>>>(
                x, mask, EH, zbp, Bint, Bleaf,
                b_iou_x, b_f_x, b_iou_h, b_f_h, h, c, hbH, s0p, Mp);
    }

    // persistent kernel for levels 11..0 (one launch, grid barrier between levels)
    tail_kernel<<<TAIL_BLOCKS, 512, 0, stream>>>(
        x, mask, EH, zbp, Bint,
        b_iou_x, b_f_x, b_iou_h, b_f_h, h, c, hbH, bar);
}

// Round 11
// 619.859 us; speedup vs baseline: 6.9674x; 1.1097x over previous
//
#include <hip/hip_runtime.h>
#include <math.h>

typedef unsigned short u16;
typedef unsigned int u32;
typedef float f32x4 __attribute__((ext_vector_type(4)));
typedef short bfrag __attribute__((ext_vector_type(8)));

#define HS 128
#define DPLANE 4096000      // EL - EH, u16 elements
#define DHB    33554304     // hbL - hbH, u16 elements (N*HS)

__device__ __forceinline__ float sigf(float x) { return 1.0f / (1.0f + __expf(-x)); }
__device__ __forceinline__ float tanhfast(float x) {
    float e = __expf(2.0f * x);
    return 1.0f - 2.0f / (e + 1.0f);
}
__device__ __forceinline__ u16 f2bf(float f) {
    u32 u = __float_as_uint(f);
    return (u16)((u + 0x7FFFu + ((u >> 16) & 1u)) >> 16);
}
__device__ __forceinline__ float bf2f(u16 h) { return __uint_as_float(((u32)h) << 16); }

template<int N> __device__ __forceinline__ void waitv() {
    asm volatile("s_waitcnt vmcnt(%0)" :: "i"(N) : "memory");
}

// B' value: rows 0-127 emb:[W_iou|W_f|W_f], 128-255 hl:[U_iou|U_f|0], 256-383 hr:[U_iou|0|U_f]
__device__ __forceinline__ float bval_int(int k, int col,
    const float* W_iou, const float* W_f, const float* U_iou, const float* U_f)
{
    if (col < 384) {
        if (k < 128) return W_iou[k * 384 + col];
        if (k < 256) return U_iou[(k - 128) * 384 + col];
        return U_iou[(k - 256) * 384 + col];
    } else if (col < 512) {
        int cc = col - 384;
        if (k < 128) return W_f[k * 128 + cc];
        if (k < 256) return U_f[(k - 128) * 128 + cc];
        return 0.0f;
    } else {
        int cc = col - 512;
        if (k < 128) return W_f[k * 128 + cc];
        if (k < 256) return 0.0f;
        return U_f[(k - 256) * 128 + cc];
    }
}

// ---------------- prep (r10 verbatim; zbf slot doubles as barrier counters) ----------------
#define TOT_INT (12 * 40 * 2 * 512)        // 491520
#define TOT_LEAF (4 * 24 * 2 * 512)        // 98304
#define ZBF_OFF (TOT_INT + TOT_LEAF)       // 589824
#define EPL_OFF (ZBF_OFF + 128)            // 589952
#define TOT_E 4096000
#define ZBP_OFF (EPL_OFF + TOT_E)          // 4685952
#define PREP_ALL (ZBP_OFF + 128)           // 4686080

__global__ __launch_bounds__(256) void prep_kernel(
    const float* __restrict__ W_iou, const float* __restrict__ W_f,
    const float* __restrict__ U_iou, const float* __restrict__ U_f,
    const float* __restrict__ E,
    u16* __restrict__ Bint, u16* __restrict__ Bleaf,
    u16* __restrict__ EH, u16* __restrict__ EL,
    u16* __restrict__ zbp, float* __restrict__ zbf)
{
    int idx = blockIdx.x * 256 + threadIdx.x;
    if (idx < TOT_INT) {
        int j8 = idx & 7, l = (idx >> 3) & 63, half = (idx >> 9) & 1;
        int rest = idx >> 10;
        int cfabs = rest % 40, kc = rest / 40;
        int wq = cfabs / 5, g = cfabs % 5;
        int j = 16 * wq + (l & 15);
        int origcol = (g < 3) ? g * 128 + j : ((g == 3) ? 384 + j : 512 + j);
        int k = kc * 32 + (l >> 4) * 8 + j8;
        float v = bval_int(k, origcol, W_iou, W_f, U_iou, U_f);
        u16 hi = f2bf(v);
        Bint[idx] = half ? f2bf(v - bf2f(hi)) : hi;
    } else if (idx < TOT_INT + TOT_LEAF) {
        int i2 = idx - TOT_INT;
        int j8 = i2 & 7, l = (i2 >> 3) & 63, half = (i2 >> 9) & 1;
        int rest = i2 >> 10;
        int cfabs = rest % 24, kc = rest / 24;
        int wq = cfabs / 3, g = cfabs % 3;
        int origcol = g * 128 + 16 * wq + (l & 15);
        int k = kc * 32 + (l >> 4) * 8 + j8;
        float v = W_iou[k * 384 + origcol];
        u16 hi = f2bf(v);
        Bleaf[i2] = half ? f2bf(v - bf2f(hi)) : hi;
    } else if (idx < EPL_OFF) {
        zbf[idx - ZBF_OFF] = 0.0f;     // also zeroes the grid-barrier counters
    } else if (idx < ZBP_OFF) {
        int i3 = idx - EPL_OFF;
        float v = E[i3];
        u16 hi = f2bf(v);
        EH[i3] = hi;
        EL[i3] = f2bf(v - bf2f(hi));
    } else if (idx < PREP_ALL) {
        zbp[idx - ZBP_OFF] = 0;
    }
}

// ---------------- one 64-row GEMM phase, B-prefetch pipelined (r10 verbatim) ----------------
template<int NKC, int NCFA, int NCF, int MODE>
__device__ __forceinline__ void phase_gemm(
    f32x4 (&acc)[4][NCF],
    const int* __restrict__ x, const int* __restrict__ mask,
    const u16* __restrict__ EH, const u16* __restrict__ zbp,
    const u16* __restrict__ hbH,
    const u16* __restrict__ Bg,
    u16* ldsA, const u16* ldsP,
    int n0, int lastn, int t)
{
    constexpr int NB = 2 * NCF;
    const int l = t & 63, wq = t >> 6;
    const int lr = l & 15, lg = l >> 4;

    const u16 *ebp, *hb1p = nullptr, *hb2p = nullptr;
    {
        const int prow = t & 63, pk8 = ((t >> 6) & 3) * 8, pp = t >> 8;
        int ns = n0 + prow; if (ns >= lastn) ns = n0;
        const u16* Ep = pp ? (EH + DPLANE) : EH;
        ebp = (mask[ns] ? Ep + (size_t)x[ns] * HS : zbp) + pk8;
        if (MODE == 1) {
            const u16* hbp = pp ? (hbH + DHB) : hbH;
            hb1p = hbp + (size_t)(2 * ns + 1) * HS + pk8;
            hb2p = hbp + (size_t)(2 * ns + 2) * HS + pk8;
        }
    }
    auto stageA = [&](int kc, int buf) {
        const u16* src;
        if (MODE == 1) {
            int seg = kc >> 2, ks = kc & 3;
            src = (seg == 0 ? ebp : (seg == 1 ? hb1p : hb2p)) + ks * 32;
        } else {
            src = ebp + (kc & 3) * 32;
        }
        __builtin_amdgcn_global_load_lds(
            (const __attribute__((address_space(1))) void*)src,
            (__attribute__((address_space(3))) void*)(ldsA + buf * 4096 + t * 8), 16, 0, 0);
    };
    const u16* bbase = Bg + (size_t)(wq * NCF) * 1024 + (size_t)l * 8;
    auto loadB = [&](int kc, bfrag (&bh)[NCF], bfrag (&bl)[NCF]) {
        const u16* bp = bbase + (size_t)kc * ((size_t)NCFA * 1024);
#pragma unroll
        for (int cf = 0; cf < NCF; ++cf) {
            bh[cf] = *(const bfrag*)(bp + (size_t)cf * 1024);
            bl[cf] = *(const bfrag*)(bp + (size_t)cf * 1024 + 512);
        }
    };
    auto compute = [&](int kk, bfrag (&bh)[NCF], bfrag (&bl)[NCF]) {
        bfrag ah[4], al[4];
        if (MODE == 2 && kk >= 4) {
            const int seg = (kk - 4) >> 2;
            const int kk8 = ((kk - 4) & 3) * 4 + lg;
#pragma unroll
            for (int rf = 0; rf < 4; ++rf) {
                int arow = 16 * rf + lr;
                ah[rf] = *(const bfrag*)(ldsP + ((size_t)kk8 * 128 + seg * 64 + arow) * 8);
                al[rf] = *(const bfrag*)(ldsP + ((size_t)(16 + kk8) * 128 + seg * 64 + arow) * 8);
            }
        } else {
            const u16* ab = ldsA + (kk % 3) * 4096;
#pragma unroll
            for (int rf = 0; rf < 4; ++rf) {
                int arow = 16 * rf + lr;
                ah[rf] = *(const bfrag*)(ab + ((size_t)lg * 64 + arow) * 8);
                al[rf] = *(const bfrag*)(ab + ((size_t)(4 + lg) * 64 + arow) * 8);
            }
        }
#pragma unroll
        for (int cf = 0; cf < NCF; ++cf) {
#pragma unroll
            for (int rf = 0; rf < 4; ++rf)
                acc[rf][cf] = __builtin_amdgcn_mfma_f32_16x16x32_bf16(ah[rf], bh[cf], acc[rf][cf], 0, 0, 0);
#pragma unroll
            for (int rf = 0; rf < 4; ++rf)
                acc[rf][cf] = __builtin_amdgcn_mfma_f32_16x16x32_bf16(al[rf], bh[cf], acc[rf][cf], 0, 0, 0);
#pragma unroll
            for (int rf = 0; rf < 4; ++rf)
                acc[rf][cf] = __builtin_amdgcn_mfma_f32_16x16x32_bf16(ah[rf], bl[cf], acc[rf][cf], 0, 0, 0);
        }
    };

    bfrag bhA[NCF], blA[NCF], bhB[NCF], blB[NCF];
    stageA(0, 0);
    loadB(0, bhA, blA);
    stageA(1, 1);

#pragma unroll 1
    for (int kc = 0; kc < NKC; kc += 2) {
        loadB(kc + 1, bhB, blB);
        if constexpr (MODE == 2) { if (kc <= 2) waitv<NB + 1>(); else waitv<NB>(); }
        else waitv<NB + 1>();
        __builtin_amdgcn_s_barrier();
        asm volatile("" ::: "memory");
        if constexpr (MODE == 2) { if (kc + 2 < 4) stageA(kc + 2, (kc + 2) % 3); }
        else                     { if (kc + 2 <= NKC - 1) stageA(kc + 2, (kc + 2) % 3); }
        compute(kc, bhA, blA);

        { int kn = kc + 2; if (kn > NKC - 1) kn = NKC - 1; loadB(kn, bhA, blA); }
        if constexpr (MODE == 2) { if (kc == 0) waitv<NB + 1>(); else waitv<NB>(); }
        else { if (kc == NKC - 2) waitv<NB>(); else waitv<NB + 1>(); }
        __builtin_amdgcn_s_barrier();
        asm volatile("" ::: "memory");
        if constexpr (MODE == 2) { if (kc + 3 < 4) stageA(kc + 3, (kc + 3) % 3); }
        else                     { if (kc + 3 <= NKC - 1) stageA(kc + 3, (kc + 3) % 3); }
        compute(kc + 1, bhB, blB);
    }
}

// ---------------- child epilogue (r10 verbatim) ----------------
template<int NCF, bool LEAF>
__device__ __forceinline__ void child_epilogue(
    f32x4 (&acc)[4][NCF],
    const int* __restrict__ mask,
    const float* __restrict__ b_iou_x, const float* __restrict__ b_f_x,
    const float* __restrict__ b_iou_h, const float* __restrict__ b_f_h,
    float* __restrict__ h, const float* __restrict__ c,
    u16* ldsP, float* ldsC,
    int n0, int lastn, int oBase, int t)
{
    const int l = t & 63, wq = t >> 6, lr = l & 15, lg = l >> 4;
    const int j = 16 * wq + lr;
    float bix = b_iou_x[j], box = b_iou_x[HS + j], bux = b_iou_x[2 * HS + j];
    float bih = b_iou_h[j], boh = b_iou_h[HS + j], buh = b_iou_h[2 * HS + j];
    float bfx = 0.0f, bfh = 0.0f;
    if constexpr (!LEAF) { bfx = b_f_x[j]; bfh = b_f_h[j]; }
#pragma unroll
    for (int rf = 0; rf < 4; ++rf) {
#pragma unroll
        for (int r = 0; r < 4; ++r) {
            int ctr = 16 * rf + 4 * lg + r;
            int n = n0 + ctr;
            if (n >= lastn) continue;
            float m = (float)mask[n];
            float iv = acc[rf][0][r] + m * bix + bih;
            float ov = acc[rf][1][r] + m * box + boh;
            float uv = acc[rf][2][r] + m * bux + buh;
            float cn;
            if constexpr (!LEAF) {
                float fl = acc[rf][3][r] + m * bfx + bfh;
                float fr = acc[rf][4][r] + m * bfx + bfh;
                float cl = c[(size_t)(2 * n + 1) * HS + j];
                float cr = c[(size_t)(2 * n + 2) * HS + j];
                cn = sigf(iv) * tanhfast(uv) + sigf(fl) * cl + sigf(fr) * cr;
            } else {
                cn = sigf(iv) * tanhfast(uv);
            }
            float hn = sigf(ov) * tanhfast(cn);
            h[(size_t)n * HS + j] = hn;
            int o = oBase + ctr;
            int half = o & 1, slot = o >> 1;
            u16 hh = f2bf(hn);
            ldsP[((size_t)(j >> 3) * 128 + half * 64 + slot) * 8 + (j & 7)] = hh;
            ldsP[((size_t)(16 + (j >> 3)) * 128 + half * 64 + slot) * 8 + (j & 7)] = f2bf(hn - bf2f(hh));
            ldsC[o * 129 + j] = cn;
        }
    }
}

// ---------------- parent epilogue (r10 verbatim) ----------------
__device__ __forceinline__ void parent_epilogue(
    f32x4 (&acc)[4][5],
    const int* __restrict__ mask,
    const float* __restrict__ b_iou_x, const float* __restrict__ b_f_x,
    const float* __restrict__ b_iou_h, const float* __restrict__ b_f_h,
    float* __restrict__ h, float* __restrict__ c, u16* __restrict__ hbH,
    const float* ldsC,
    int n0, int lastn, int t)
{
    u16* hbL = hbH + DHB;
    const int l = t & 63, wq = t >> 6, lr = l & 15, lg = l >> 4;
    const int j = 16 * wq + lr;
    float bix = b_iou_x[j], box = b_iou_x[HS + j], bux = b_iou_x[2 * HS + j];
    float bih = b_iou_h[j], boh = b_iou_h[HS + j], buh = b_iou_h[2 * HS + j];
    float bfx = b_f_x[j], bfh = b_f_h[j];
#pragma unroll
    for (int rf = 0; rf < 4; ++rf) {
#pragma unroll
        for (int r = 0; r < 4; ++r) {
            int ctr = 16 * rf + 4 * lg + r;
            int n = n0 + ctr;
            if (n >= lastn) continue;
            float m = (float)mask[n];
            float iv = acc[rf][0][r] + m * bix + bih;
            float ov = acc[rf][1][r] + m * box + boh;
            float uv = acc[rf][2][r] + m * bux + buh;
            float fl = acc[rf][3][r] + m * bfx + bfh;
            float fr = acc[rf][4][r] + m * bfx + bfh;
            float cl = ldsC[(2 * ctr) * 129 + j];
            float cr = ldsC[(2 * ctr + 1) * 129 + j];
            float cn = sigf(iv) * tanhfast(uv) + sigf(fl) * cl + sigf(fr) * cr;
            float hn = sigf(ov) * tanhfast(cn);
            c[(size_t)n * HS + j] = cn;
            h[(size_t)n * HS + j] = hn;
            u16 hh = f2bf(hn);
            hbH[(size_t)n * HS + j] = hh;
            hbL[(size_t)n * HS + j] = f2bf(hn - bf2f(hh));
        }
    }
}

// ---------------- fused (parent, child) level-pair kernel (r10 verbatim) ----------------
template<bool LEAFCH>
__global__ __launch_bounds__(512, 2) void fused_pair(
    const int* __restrict__ x, const int* __restrict__ mask,
    const u16* __restrict__ EH, const u16* __restrict__ zbp,
    const u16* __restrict__ Bint, const u16* __restrict__ Bleaf,
    const float* __restrict__ b_iou_x, const float* __restrict__ b_f_x,
    const float* __restrict__ b_iou_h, const float* __restrict__ b_f_h,
    float* __restrict__ h, float* __restrict__ c, u16* __restrict__ hbH,
    int s0p, int Mp)
{
    __shared__ __align__(16) u16 ldsA[3 * 4096];
    __shared__ __align__(16) u16 ldsP[2 * 16 * 128 * 8];
    __shared__ __align__(16) float ldsC[128 * 129];
    const int t = threadIdx.x;
    const int p0 = s0p + blockIdx.x * 64;
    const int lastp = s0p + Mp;
    const int lastc = 2 * lastp + 1;

    constexpr int CNCF = LEAFCH ? 3 : 5;
    const f32x4 zzz = {0.0f, 0.0f, 0.0f, 0.0f};

    {
        f32x4 acc[4][CNCF];
#pragma unroll
        for (int rf = 0; rf < 4; ++rf)
#pragma unroll
            for (int cf = 0; cf < CNCF; ++cf) acc[rf][cf] = zzz;
        phase_gemm<LEAFCH ? 4 : 12, LEAFCH ? 24 : 40, CNCF, LEAFCH ? 0 : 1>(
            acc, x, mask, EH, zbp, hbH, LEAFCH ? Bleaf : Bint, ldsA, ldsP, 2 * p0 + 1, lastc, t);
        child_epilogue<CNCF, LEAFCH>(acc, mask, b_iou_x, b_f_x, b_iou_h, b_f_h,
                                     h, c, ldsP, ldsC, 2 * p0 + 1, lastc, 0, t);
    }
    __syncthreads();
    {
        f32x4 acc[4][CNCF];
#pragma unroll
        for (int rf = 0; rf < 4; ++rf)
#pragma unroll
            for (int cf = 0; cf < CNCF; ++cf) acc[rf][cf] = zzz;
        phase_gemm<LEAFCH ? 4 : 12, LEAFCH ? 24 : 40, CNCF, LEAFCH ? 0 : 1>(
            acc, x, mask, EH, zbp, hbH, LEAFCH ? Bleaf : Bint, ldsA, ldsP, 2 * p0 + 65, lastc, t);
        child_epilogue<CNCF, LEAFCH>(acc, mask, b_iou_x, b_f_x, b_iou_h, b_f_h,
                                     h, c, ldsP, ldsC, 2 * p0 + 65, lastc, 64, t);
    }
    __syncthreads();
    {
        f32x4 acc[4][5];
#pragma unroll
        for (int rf = 0; rf < 4; ++rf)
#pragma unroll
            for (int cf = 0; cf < 5; ++cf) acc[rf][cf] = zzz;
        phase_gemm<12, 40, 5, 2>(acc, x, mask, EH, zbp, hbH, Bint, ldsA, ldsP, p0, lastp, t);
        parent_epilogue(acc, mask, b_iou_x, b_f_x, b_iou_h, b_f_h,
                        h, c, hbH, ldsC, p0, lastp, t);
    }
}

// ---------------- persistent tail kernel: levels 11..0, B resident in LDS ----------------
// Grid: 40 blocks = 8 column-groups (wq: 16 cols x 5 gates, 120KB B slice in LDS)
//                 x 5 row-groups (128-row tiles round-robin).
// Per tile: 8 waves, wave w = rows 16w..16w+16, acc = 5 f32x4.
#define TAIL_BLOCKS 40

__device__ __forceinline__ void grid_barrier(u32* ctr, u32 target, int t) {
    __syncthreads();
    if (t == 0) {
        __threadfence();
        __hip_atomic_fetch_add(ctr, 1u, __ATOMIC_RELEASE, __HIP_MEMORY_SCOPE_AGENT);
        while (__hip_atomic_load(ctr, __ATOMIC_ACQUIRE, __HIP_MEMORY_SCOPE_AGENT) < target)
            __builtin_amdgcn_s_sleep(4);
        __threadfence();
    }
    __syncthreads();
}

__global__ __launch_bounds__(512, 2) void tail_kernel(
    const int* __restrict__ x, const int* __restrict__ mask,
    const u16* __restrict__ EH, const u16* __restrict__ zbp,
    const u16* __restrict__ Bint,
    const float* __restrict__ b_iou_x, const float* __restrict__ b_f_x,
    const float* __restrict__ b_iou_h, const float* __restrict__ b_f_h,
    float* __restrict__ h, float* __restrict__ c, u16* __restrict__ hbH,
    u32* __restrict__ bar)
{
    __shared__ __align__(16) u16 ldsB[120 * 512];   // 120 KB: B slice for wq (5 cfabs x 12 kc x 2 halves)
    __shared__ __align__(16) u16 ldsA[2 * 8192];    // 32 KB: A planes, 2 bufs x (2 plane x 4 kslot x 128 row x 8)
    const int t = threadIdx.x;
    const int wq = blockIdx.x & 7;
    const int rg = blockIdx.x >> 3;        // 0..4
    const int l = t & 63, w = t >> 6;
    const int lr = l & 15, lg = l >> 4;
    u16* hbL = hbH + DHB;

    // ---- one-time B preload: 120 segments of 1KB ----
    for (int rr = 0; rr < 15; ++rr) {
        int s = rr * 8 + w;                          // 0..119
        int kcq = s / 10, rem = s % 10, cf = rem >> 1, half = rem & 1;
        const u16* src = Bint + ((size_t)((kcq * 40 + wq * 5 + cf) * 2 + half)) * 512 + l * 8;
        *(bfrag*)(ldsB + (size_t)s * 512 + l * 8) = *(const bfrag*)src;
    }
    __syncthreads();

    // per-lane output column (fixed for whole kernel)
    const int j = 16 * wq + lr;
    const float bix = b_iou_x[j], box = b_iou_x[HS + j], bux = b_iou_x[2 * HS + j];
    const float bih = b_iou_h[j], boh = b_iou_h[HS + j], buh = b_iou_h[2 * HS + j];
    const float bfx = b_f_x[j], bfh = b_f_h[j];

    const int row = t & 127, kslot = (t >> 7) & 3;
    const f32x4 zzz = {0.0f, 0.0f, 0.0f, 0.0f};

#pragma unroll 1
    for (int lvl = 11; lvl >= 0; --lvl) {
        const int s0 = (1 << lvl) - 1, M = 1 << lvl;
        const int lastn = s0 + M;
        const int ntiles = (M + 127) >> 7;
#pragma unroll 1
        for (int tile = rg; tile < ntiles; tile += 5) {
            const int n0 = s0 + tile * 128;
            // per-thread DMA sources for this tile
            int ns = n0 + row; if (ns >= lastn) ns = n0;
            const int mk = mask[ns];
            const u16* pE = (mk ? EH + (size_t)x[ns] * HS : zbp) + kslot * 8;
            const int dE = mk ? DPLANE : 0;
            const u16* p1 = hbH + (size_t)(2 * ns + 1) * HS + kslot * 8;
            const u16* p2 = hbH + (size_t)(2 * ns + 2) * HS + kslot * 8;

            auto stageA = [&](int kc, int buf) {
                const u16 *sh; int dd;
                int ks = kc & 3;
                if (kc < 4)      { sh = pE + ks * 32; dd = dE; }
                else if (kc < 8) { sh = p1 + ks * 32; dd = DHB; }
                else             { sh = p2 + ks * 32; dd = DHB; }
                u16* d = ldsA + buf * 8192 + t * 8;
                __builtin_amdgcn_global_load_lds(
                    (const __attribute__((address_space(1))) void*)sh,
                    (__attribute__((address_space(3))) void*)d, 16, 0, 0);
                __builtin_amdgcn_global_load_lds(
                    (const __attribute__((address_space(1))) void*)(sh + dd),
                    (__attribute__((address_space(3))) void*)(d + 4096), 16, 0, 0);
            };

            f32x4 acc[5];
#pragma unroll
            for (int cf = 0; cf < 5; ++cf) acc[cf] = zzz;

            stageA(0, 0);
            stageA(1, 1);
#pragma unroll 1
            for (int kc = 0; kc < 12; ++kc) {
                if (kc < 11) waitv<2>(); else waitv<0>();
                __builtin_amdgcn_s_barrier();
                asm volatile("" ::: "memory");
                const u16* ab = ldsA + (kc & 1) * 8192;
                const int arow = 16 * w + lr;
                bfrag ah = *(const bfrag*)(ab + ((size_t)lg * 128 + arow) * 8);
                bfrag al = *(const bfrag*)(ab + ((size_t)(512 + lg * 128 + arow)) * 8);
                const u16* bb = ldsB + (size_t)kc * (10 * 512) + l * 8;
#pragma unroll
                for (int cf = 0; cf < 5; ++cf) {
                    bfrag bh = *(const bfrag*)(bb + (size_t)(2 * cf) * 512);
                    bfrag bl = *(const bfrag*)(bb + (size_t)(2 * cf + 1) * 512);
                    acc[cf] = __builtin_amdgcn_mfma_f32_16x16x32_bf16(ah, bh, acc[cf], 0, 0, 0);
                    acc[cf] = __builtin_amdgcn_mfma_f32_16x16x32_bf16(al, bh, acc[cf], 0, 0, 0);
                    acc[cf] = __builtin_amdgcn_mfma_f32_16x16x32_bf16(ah, bl, acc[cf], 0, 0, 0);
                }
                __builtin_amdgcn_s_barrier();
                asm volatile("" ::: "memory");
                if (kc + 2 < 12) stageA(kc + 2, kc & 1);
            }

            // ---- epilogue: rows 16w + lg*4 + r, column j ----
#pragma unroll
            for (int r = 0; r < 4; ++r) {
                int n = n0 + 16 * w + 4 * lg + r;
                if (n >= lastn) continue;
                float m = (float)mask[n];
                float iv = acc[0][r] + m * bix + bih;
                float ov = acc[1][r] + m * box + boh;
                float uv = acc[2][r] + m * bux + buh;
                float fl = acc[3][r] + m * bfx + bfh;
                float fr = acc[4][r] + m * bfx + bfh;
                float cl = c[(size_t)(2 * n + 1) * HS + j];
                float cr = c[(size_t)(2 * n + 2) * HS + j];
                float cn = sigf(iv) * tanhfast(uv) + sigf(fl) * cl + sigf(fr) * cr;
                float hn = sigf(ov) * tanhfast(cn);
                c[(size_t)n * HS + j] = cn;
                h[(size_t)n * HS + j] = hn;
                u16 hh = f2bf(hn);
                hbH[(size_t)n * HS + j] = hh;
                hbL[(size_t)n * HS + j] = f2bf(hn - bf2f(hh));
            }
        }
        if (lvl > 0) grid_barrier(&bar[11 - lvl], TAIL_BLOCKS, t);
    }
}

extern "C" void kernel_launch(void* const* d_in, const int* in_sizes, int n_in,
                              void* d_out, int out_size, void* d_ws, size_t ws_size,
                              hipStream_t stream)
{
    const int*   x       = (const int*)d_in[0];
    const int*   mask    = (const int*)d_in[1];
    const float* E       = (const float*)d_in[2];
    const float* W_iou   = (const float*)d_in[3];
    const float* b_iou_x = (const float*)d_in[4];
    const float* W_f     = (const float*)d_in[5];
    const float* b_f_x   = (const float*)d_in[6];
    const float* U_iou   = (const float*)d_in[7];
    const float* b_iou_h = (const float*)d_in[8];
    const float* U_f     = (const float*)d_in[9];
    const float* b_f_h   = (const float*)d_in[10];

    float* h = (float*)d_out;
    char* ws = (char*)d_ws;

    u16*   Bint  = (u16*)(ws);                      // 983,040
    u16*   Bleaf = (u16*)(ws + 983040);             // 196,608 -> 1,179,648
    float* zbf   = (float*)(ws + 1179648);          // 512     -> 1,180,160 (barrier ctrs live here)
    u32*   bar   = (u32*)(ws + 1179648);            // zeroed by prep each launch
    u16*   EH    = (u16*)(ws + 1180160);            // 8,192,000  -> 9,372,160
    u16*   EL    = (u16*)(ws + 9372160);            // 8,192,000  -> 17,564,160 (EH + DPLANE)
    u16*   zbp   = (u16*)(ws + 17564160);           // 256        -> 17,564,416
    float* c     = (float*)(ws + 17564416);         // 134,217,216 -> 151,781,632
    u16*   hbH   = (u16*)(ws + 151781632);          // 2 x 67,108,608 -> 285,998,848 (hbL = hbH + DHB)

    prep_kernel<<<PREP_ALL / 256, 256, 0, stream>>>(
        W_iou, W_f, U_iou, U_f, E, Bint, Bleaf, EH, EL, zbp, zbf);

    // fused (parent, child) pairs for the big levels: (16,17), (14,15), (12,13)
    for (int lvl = 16; lvl >= 12; lvl -= 2) {
        int s0p = (1 << lvl) - 1, Mp = 1 << lvl;
        int blocks = (Mp + 63) / 64;
        if (lvl == 16)
            fused_pair<true><<<blocks, 512, 0, stream>>>(
                x, mask, EH, zbp, Bint, Bleaf,
                b_iou_x, b_f_x, b_iou_h, b_f_h, h, c, hbH, s0p, Mp);
        else
            fused_pair<false><<<blocks, 512, 0, stream>>>(
                x, mask, EH, zbp, Bint, Bleaf,
                b_iou_x, b_f_x, b_iou_h, b_f_h, h, c, hbH, s0p, Mp);
    }

    // persistent tail: levels 11..0, B LDS-resident, grid barrier between levels
    tail_kernel<<<TAIL_BLOCKS, 512, 0, stream>>>(
        x, mask, EH, zbp, Bint,
        b_iou_x, b_f_x, b_iou_h, b_f_h, h, c, hbH, bar);
}